// Round 2
// baseline (894.096 us; speedup 1.0000x reference)
//
#include <hip/hip_runtime.h>
#include <hip/hip_cooperative_groups.h>
#include <hip/hip_bf16.h>
#include <hip/hip_fp16.h>

// Storage-dtype-templated load: DT=0 bf16, DT=1 fp16, DT=2 f32.
template <int DT>
__device__ __forceinline__ float ldT(const void* p, long i) {
  if (DT == 0) {
    unsigned int a = ((unsigned int)((const unsigned short*)p)[i]) << 16;
    union { unsigned int u; float f; } c; c.u = a; return c.f;
  } else if (DT == 1) {
    return __half2float(((const __half*)p)[i]);
  } else {
    return ((const float*)p)[i];
  }
}
template <int DT>
__device__ __forceinline__ bool msknzT(const void* p, long i) {
  if (DT < 2) return ((const unsigned short*)p)[i] != 0;  // 0.0 encodes as 0x0000
  return ((const float*)p)[i] != 0.f;
}
__device__ __forceinline__ float wred64(float v) {
#pragma unroll
  for (int off = 1; off < 64; off <<= 1) v += __shfl_xor(v, off, 64);
  return v;
}
// wave-uniform broadcast of lane l's value (v_readlane -> SGPR operand)
__device__ __forceinline__ float bcastlane(float v, int l) {
  return __int_as_float(__builtin_amdgcn_readlane(__float_as_int(v), l));
}
__device__ __forceinline__ void ct67_itab(int bi, int& i, int& t) {
  const int toff[8] = {0, 1536, 4608, 6144, 9216, 10752, 13824, 15360};
  i = 0;
  while (bi >= toff[i + 1]) i++;
  t = bi - toff[i];
}
template <int DT>
__device__ __forceinline__ void ct67_mask(int i, const void* adj00, const void* b01,
                                          const void* adj11, const void* b12,
                                          const void* adj22, const void*& mp,
                                          long& mts, long& mss) {
  switch (i) {
    case 0: mp = adj00; mts = 1536; mss = 1; break;
    case 1: mp = b01;   mts = 1;    mss = 3072; break;
    case 2: mp = b01;   mts = 3072; mss = 1; break;
    case 3: mp = adj11; mts = 3072; mss = 1; break;
    case 4: mp = b12;   mts = 1;    mss = 1536; break;
    case 5: mp = b12;   mts = 1536; mss = 1; break;
    default: mp = adj22; mts = 1536; mss = 1; break;
  }
}
__device__ __forceinline__ void gsync() {
  cooperative_groups::this_grid().sync();
}

// ======================= cooperative mega-kernel =======================
struct CTP {
  const void *x0, *pe0; const int* bel0;
  const void *x1, *pe1; const int* bel1;
  const void *x2, *pe2; const int* bel2;
  const void *adj00, *adj11, *adj22, *b01, *b12;
  const void *Wf0, *bf0, *Wp0, *Wf1, *bf1, *Wp1, *Wf2, *bf2, *Wp2;
  const void *Wq, *bq, *Wk, *bk, *Wv, *bv, *Wo, *bo;
  const void *g1, *be1, *g2, *be2, *Wff1, *bff1, *Wff2, *bff2;
  const void *Wh1, *bh1, *Wh2, *bh2, *Wh3, *bh3;
  float *hbuf, *obuf, *qb, *kb, *vb, *ppart;
  int *ell, *nnz;
  float* out;
  int ellok;
};

template <int DT>
__device__ void mega_body(const CTP p, float* smem, const int* s_rng) {
  int tid = threadIdx.x;
  int lane = tid & 63, wid = tid >> 6;
  int gw = blockIdx.x * 4 + wid;  // global wave id, 0..2047

  // ---------------- stage A: embed + ELL build ----------------
  for (int row = gw; row < 6144; row += 2048) {
    int d = (row < 1536) ? 0 : ((row < 4608) ? 1 : 2);
    int r = row - ((d == 0) ? 0 : ((d == 1) ? 1536 : 4608));
    const void* x  = (d == 0) ? p.x0  : ((d == 1) ? p.x1  : p.x2);
    const void* pe = (d == 0) ? p.pe0 : ((d == 1) ? p.pe1 : p.pe2);
    const void* wf = (d == 0) ? p.Wf0 : ((d == 1) ? p.Wf1 : p.Wf2);
    const void* bf = (d == 0) ? p.bf0 : ((d == 1) ? p.bf1 : p.bf2);
    const void* wp = (d == 0) ? p.Wp0 : ((d == 1) ? p.Wp1 : p.Wp2);
    float acc = ldT<DT>(bf, lane);
#pragma unroll 8
    for (int f = 0; f < 32; f++)
      acc += ldT<DT>(x, (long)r * 32 + f) * ldT<DT>(wf, f * 64 + lane);
#pragma unroll 8
    for (int q = 0; q < 16; q++)
      acc += ldT<DT>(pe, (long)r * 16 + q) * ldT<DT>(wp, q * 64 + lane);
    p.hbuf[(long)row * 64 + lane] = acc;
  }
  if (p.ellok) {
    const int sdv[7] = {0, 0, 1, 1, 1, 2, 2};
    const int tdv[7] = {0, 1, 0, 1, 2, 1, 2};
    for (int bi = gw; bi < 15360; bi += 2048) {
      int i, t;
      ct67_itab(bi, i, t);
      const void* mp; long mts, mss;
      ct67_mask<DT>(i, p.adj00, p.b01, p.adj11, p.b12, p.adj22, mp, mts, mss);
      const int* belt = (tdv[i] == 0) ? p.bel0 : ((tdv[i] == 1) ? p.bel1 : p.bel2);
      int b = belt[t];
      if (b < 0) b = 0;
      if (b > 7) b = 7;
      const int* rng = s_rng + sdv[i] * 16;
      int s0 = rng[b * 2], s1 = rng[b * 2 + 1];
      int base = 0;
      for (int s = s0; s < s1; s += 64) {
        int ss = s + lane;
        bool pred = false;
        if (ss < s1) pred = msknzT<DT>(mp, (long)t * mts + (long)ss * mss);
        unsigned long long bal = __ballot(pred);
        int pos = __popcll(bal & ((1ull << lane) - 1ull));
        if (pred && base + pos < 128) p.ell[(long)bi * 128 + base + pos] = ss;
        base += __popcll(bal);
      }
      if (lane == 0) p.nnz[bi] = base;
    }
  }
  gsync();

  for (int l = 0; l < 2; l++) {
    // ---------------- qkv: units of 32 rows (4 waves x 8 rows) ----------------
    {
      const int segend[21] = {1536, 3072, 4608, 7680, 9216, 10752, 12288, 15360, 18432,
                              21504, 24576, 27648, 29184, 32256, 35328, 38400, 39936,
                              41472, 43008, 44544, 46080};
      const int segsrc[21] = {0, 0, 0, 1, 0, 0, 0, 1, 1, 1, 1, 1, 2, 1, 1, 1, 2, 2, 2, 2, 2};
      const int segdst[21] = {0, 0, 0, 1536, 1536, 1536, 4608, 3072, 3072, 6144, 6144, 6144,
                              9216, 9216, 9216, 10752, 12288, 12288, 13824, 13824, 13824};
      const int rowoff[3] = {0, 1536, 4608};
      for (int u = blockIdx.x; u < 1440; u += 512) {
        __syncthreads();
        int gbase = u * 32;
        int seg = 0;
        while (gbase >= segend[seg]) seg++;
        int segstart = (seg == 0) ? 0 : segend[seg - 1];
        int i = seg / 3, role = seg - i * 3;
        const void* W = (role == 0) ? p.Wq : (role == 1) ? p.Wk : p.Wv;
        const void* bbp = (role == 0) ? p.bq : (role == 1) ? p.bk : p.bv;
        long wbase = (long)(l * 7 + i) * 4096;
#pragma unroll
        for (int kkk = 0; kkk < 16; kkk++)
          smem[tid + kkk * 256] = ldT<DT>(W, wbase + tid + kkk * 256);
        int rbase = gbase - segstart + wid * 8;
        int hrow0 = rowoff[segsrc[seg]] + rbase;
        float hreg[8];
#pragma unroll
        for (int rr = 0; rr < 8; rr++) hreg[rr] = p.hbuf[(long)(hrow0 + rr) * 64 + lane];
        __syncthreads();
        float bias = ldT<DT>(bbp, (long)(l * 7 + i) * 64 + lane);
        float acc[8];
#pragma unroll
        for (int rr = 0; rr < 8; rr++) acc[rr] = bias;
#pragma unroll 8
        for (int kk = 0; kk < 64; kk++) {
          float wv = smem[kk * 64 + lane];
#pragma unroll
          for (int rr = 0; rr < 8; rr++)
            acc[rr] += bcastlane(hreg[rr], kk) * wv;
        }
        float* dst = (role == 0) ? p.qb : (role == 1) ? p.kb : p.vb;
#pragma unroll
        for (int rr = 0; rr < 8; rr++)
          dst[(long)(segdst[seg] + rbase + rr) * 64 + lane] = acc[rr];
      }
    }
    gsync();
    // ---------------- attention + Wo projection: units of 4 rows ----------------
    {
      const int koff[7] = {0, 1536, 3072, 6144, 9216, 12288, 13824};
      const int sdv[7] = {0, 0, 1, 1, 1, 2, 2};
      const int tdv[7] = {0, 1, 0, 1, 2, 1, 2};
      for (int u = blockIdx.x; u < 3840; u += 512) {
        __syncthreads();
        int bi = u * 4 + wid;
        int i0, t0;
        ct67_itab(u * 4, i0, t0);
        long wobase = (long)(l * 7 + i0) * 4096;
        for (int idx = tid; idx < 4096; idx += 256) smem[idx] = ldT<DT>(p.Wo, wobase + idx);
        int i, t;
        ct67_itab(bi, i, t);
        int hh = lane / 8, jj = lane % 8;
        const float4* qp = (const float4*)(p.qb + (long)bi * 64 + hh * 8);
        float4 q0 = qp[0], q1 = qp[1];
        const float* kbase = p.kb + (long)koff[i] * 64 + hh * 8;
        const float* vbase = p.vb + (long)koff[i] * 64 + hh * 8;
        float mr = -1e30f, lr = 0.f, o[8];
#pragma unroll
        for (int d = 0; d < 8; d++) o[d] = 0.f;
        int n = p.ellok ? p.nnz[bi] : 129;
        if (n <= 128) {
          const int* hl = p.ell + (long)bi * 128;
          for (int hidx = jj; hidx < n; hidx += 8) {
            int s = hl[hidx];
            const float4* kp = (const float4*)(kbase + (long)s * 64);
            float4 k0 = kp[0], k1 = kp[1];
            float sc = q0.x * k0.x + q0.y * k0.y + q0.z * k0.z + q0.w * k0.w +
                       q1.x * k1.x + q1.y * k1.y + q1.z * k1.z + q1.w * k1.w;
            sc *= 0.35355339059327373f;
            float nm = fmaxf(mr, sc);
            float fo = expf(mr - nm);
            float wv = expf(sc - nm);
            lr = lr * fo + wv;
            const float4* vp = (const float4*)(vbase + (long)s * 64);
            float4 v0 = vp[0], v1 = vp[1];
            o[0] = o[0] * fo + wv * v0.x; o[1] = o[1] * fo + wv * v0.y;
            o[2] = o[2] * fo + wv * v0.z; o[3] = o[3] * fo + wv * v0.w;
            o[4] = o[4] * fo + wv * v1.x; o[5] = o[5] * fo + wv * v1.y;
            o[6] = o[6] * fo + wv * v1.z; o[7] = o[7] * fo + wv * v1.w;
            mr = nm;
          }
        } else {  // fallback: in-loop mask scan
          const void* mp; long mts, mss;
          ct67_mask<DT>(i, p.adj00, p.b01, p.adj11, p.b12, p.adj22, mp, mts, mss);
          const int* belt = (tdv[i] == 0) ? p.bel0 : ((tdv[i] == 1) ? p.bel1 : p.bel2);
          int b = belt[t];
          if (b < 0) b = 0;
          if (b > 7) b = 7;
          const int* rng = s_rng + sdv[i] * 16;
          int s0 = rng[b * 2], s1 = rng[b * 2 + 1];
          for (int s = s0 + jj; s < s1; s += 8) {
            if (msknzT<DT>(mp, (long)t * mts + (long)s * mss)) {
              const float4* kp = (const float4*)(kbase + (long)s * 64);
              float4 k0 = kp[0], k1 = kp[1];
              float sc = q0.x * k0.x + q0.y * k0.y + q0.z * k0.z + q0.w * k0.w +
                         q1.x * k1.x + q1.y * k1.y + q1.z * k1.z + q1.w * k1.w;
              sc *= 0.35355339059327373f;
              float nm = fmaxf(mr, sc);
              float fo = expf(mr - nm);
              float wv = expf(sc - nm);
              lr = lr * fo + wv;
              const float4* vp = (const float4*)(vbase + (long)s * 64);
              float4 v0 = vp[0], v1 = vp[1];
              o[0] = o[0] * fo + wv * v0.x; o[1] = o[1] * fo + wv * v0.y;
              o[2] = o[2] * fo + wv * v0.z; o[3] = o[3] * fo + wv * v0.w;
              o[4] = o[4] * fo + wv * v1.x; o[5] = o[5] * fo + wv * v1.y;
              o[6] = o[6] * fo + wv * v1.z; o[7] = o[7] * fo + wv * v1.w;
              mr = nm;
            }
          }
        }
#pragma unroll
        for (int off = 1; off < 8; off <<= 1) {
          float m2 = __shfl_xor(mr, off, 64);
          float l2 = __shfl_xor(lr, off, 64);
          float nm = fmaxf(mr, m2);
          float f1 = expf(mr - nm), f2 = expf(m2 - nm);
          lr = lr * f1 + l2 * f2;
#pragma unroll
          for (int d = 0; d < 8; d++) {
            float o2 = __shfl_xor(o[d], off, 64);
            o[d] = o[d] * f1 + o2 * f2;
          }
          mr = nm;
        }
        float val[8];
#pragma unroll
        for (int d = 0; d < 8; d++) val[d] = (lr > 0.f) ? (o[d] / lr) : 0.f;
        __syncthreads();
        float acc = ldT<DT>(p.bo, (long)(l * 7 + i) * 64 + lane);
        for (int g = 0; g < 8; g++) {
#pragma unroll
          for (int e = 0; e < 8; e++) {
            float sv = bcastlane(val[e], g * 8);
            acc += sv * smem[(g * 8 + e) * 64 + lane];
          }
        }
        p.obuf[(long)bi * 64 + lane] = acc;
      }
    }
    gsync();
    // ---------------- fused FFN: units of 8 rows ----------------
    {
      float* sh = smem;          // [8][64]
      float* sf = smem + 512;    // [8][256]
      float* sp = smem + 2560;   // [4][8][64]
      for (int u = blockIdx.x; u < 768; u += 512) {
        __syncthreads();
        int row0 = u * 8;
        int d = (row0 < 1536) ? 0 : ((row0 < 4608) ? 1 : 2);
        long gb = (long)(l * 3 + d) * 64;
        for (int rr = 0; rr < 2; rr++) {
          int r = wid * 2 + rr;
          int row = row0 + r;
          float x = p.hbuf[(long)row * 64 + lane];
          if (d == 0) {
            int rw = row;
            x += p.obuf[(long)rw * 64 + lane] + p.obuf[(long)(4608 + rw) * 64 + lane];
          } else if (d == 1) {
            int rw = row - 1536;
            x += p.obuf[(long)(1536 + rw) * 64 + lane] + p.obuf[(long)(6144 + rw) * 64 + lane] +
                 p.obuf[(long)(10752 + rw) * 64 + lane];
          } else {
            int rw = row - 4608;
            x += p.obuf[(long)(9216 + rw) * 64 + lane] + p.obuf[(long)(13824 + rw) * 64 + lane];
          }
          float mu = wred64(x) * 0.015625f;
          float dx = x - mu;
          float var = wred64(dx * dx) * 0.015625f;
          sh[r * 64 + lane] =
              dx * rsqrtf(var + 1e-5f) * ldT<DT>(p.g1, gb + lane) + ldT<DT>(p.be1, gb + lane);
        }
        __syncthreads();
        float hreg[8];
#pragma unroll
        for (int r = 0; r < 8; r++) hreg[r] = sh[r * 64 + lane];
        long wb1 = (long)(l * 3 + d) * 16384;
        float bb1 = ldT<DT>(p.bff1, (long)(l * 3 + d) * 256 + tid);
        float acc1[8];
#pragma unroll
        for (int r = 0; r < 8; r++) acc1[r] = bb1;
#pragma unroll 8
        for (int kk = 0; kk < 64; kk++) {
          float wv = ldT<DT>(p.Wff1, wb1 + kk * 256 + tid);
#pragma unroll
          for (int r = 0; r < 8; r++) acc1[r] += bcastlane(hreg[r], kk) * wv;
        }
#pragma unroll
        for (int r = 0; r < 8; r++) sf[r * 256 + tid] = fmaxf(acc1[r], 0.f);
        __syncthreads();
        int k0 = wid * 64;
        float sreg[8];
#pragma unroll
        for (int r = 0; r < 8; r++) sreg[r] = sf[r * 256 + k0 + lane];
        long wb2 = (long)(l * 3 + d) * 16384;
        float a2[8];
#pragma unroll
        for (int r = 0; r < 8; r++) a2[r] = 0.f;
#pragma unroll 8
        for (int kk = 0; kk < 64; kk++) {
          float w2 = ldT<DT>(p.Wff2, wb2 + (long)(k0 + kk) * 64 + lane);
#pragma unroll
          for (int r = 0; r < 8; r++) a2[r] += bcastlane(sreg[r], kk) * w2;
        }
#pragma unroll
        for (int r = 0; r < 8; r++) sp[wid * 512 + r * 64 + lane] = a2[r];
        __syncthreads();
        for (int rr = 0; rr < 2; rr++) {
          int r = wid * 2 + rr;
          int row = row0 + r;
          float x = sh[r * 64 + lane] + ldT<DT>(p.bff2, gb + lane) +
                    sp[r * 64 + lane] + sp[512 + r * 64 + lane] +
                    sp[1024 + r * 64 + lane] + sp[1536 + r * 64 + lane];
          float mu = wred64(x) * 0.015625f;
          float dx = x - mu;
          float var = wred64(dx * dx) * 0.015625f;
          p.hbuf[(long)row * 64 + lane] =
              dx * rsqrtf(var + 1e-5f) * ldT<DT>(p.g2, gb + lane) + ldT<DT>(p.be2, gb + lane);
        }
      }
    }
    gsync();
  }
  // ---------------- pooling partials ----------------
  if (gw < 256) {
    int b = gw >> 5, c = gw & 31;
    float s = 0.f;
    for (int d = 0; d < 3; d++) {
      int st = s_rng[(d * 8 + b) * 2], en = s_rng[(d * 8 + b) * 2 + 1];
      int ro = (d == 0) ? 0 : ((d == 1) ? 1536 : 4608);
      for (int r = st + c; r < en; r += 32) s += p.hbuf[(long)(ro + r) * 64 + lane];
    }
    p.ppart[(long)(b * 32 + c) * 64 + lane] = s;
  }
  gsync();
  // ---------------- final pool + head MLP (block 0) ----------------
  if (blockIdx.x == 0) {
    float* pooled = smem;        // [8][64]
    float* y1 = smem + 512;
    float* y2 = smem + 1024;
    __syncthreads();
    for (int pass = 0; pass < 2; pass++) {
      int b = wid + pass * 4;
      float s = 0.f;
      for (int c = 0; c < 32; c++) s += p.ppart[(long)(b * 32 + c) * 64 + lane];
      int cnt = 0;
      for (int d = 0; d < 3; d++)
        cnt += s_rng[(d * 8 + b) * 2 + 1] - s_rng[(d * 8 + b) * 2];
      pooled[b * 64 + lane] = (cnt > 0) ? (s / (float)cnt) : 0.f;
    }
    __syncthreads();
    for (int pass = 0; pass < 2; pass++) {
      int b = wid + pass * 4;
      float acc = ldT<DT>(p.bh1, lane);
      for (int kk = 0; kk < 64; kk++) acc += pooled[b * 64 + kk] * ldT<DT>(p.Wh1, kk * 64 + lane);
      y1[b * 64 + lane] = fmaxf(acc, 0.f);
    }
    __syncthreads();
    for (int pass = 0; pass < 2; pass++) {
      int b = wid + pass * 4;
      float acc = ldT<DT>(p.bh2, lane);
      for (int kk = 0; kk < 64; kk++) acc += y1[b * 64 + kk] * ldT<DT>(p.Wh2, kk * 64 + lane);
      y2[b * 64 + lane] = fmaxf(acc, 0.f);
    }
    __syncthreads();
    for (int pass = 0; pass < 2; pass++) {
      int b = wid + pass * 4;
      if (lane < 10) {
        float o = ldT<DT>(p.bh3, lane);
        for (int kk = 0; kk < 64; kk++) o += y2[b * 64 + kk] * ldT<DT>(p.Wh3, kk * 10 + lane);
        p.out[b * 10 + lane] = o;
      }
    }
  }
}

__global__ __launch_bounds__(256, 2) void CellularTransformer_67345087201410_kernel(CTP p) {
  __shared__ float smem[4608];
  __shared__ int s_rng[48];
  __shared__ int s_dt;
  int tid = threadIdx.x;
  if (tid == 0) {  // serial classify: bit-identical decision to ct67_init
    const unsigned short* x0u = (const unsigned short*)p.x0;
    float vals[32], mean = 0.f, var = 0.f;
    for (int i = 0; i < 32; i++) {
      union { unsigned int u; float f; } c;
      c.u = ((unsigned int)x0u[i]) << 16;
      vals[i] = c.f; mean += c.f;
    }
    mean /= 32.f;
    for (int i = 0; i < 32; i++) var += (vals[i] - mean) * (vals[i] - mean);
    var /= 32.f;
    s_dt = (var < 1e-6f) ? 1 : ((var < 1e3f) ? 0 : 2);
  }
  if (tid >= 64 && tid < 88) {
    int t = tid - 64;
    int d = t / 8, b = t % 8;
    const int* bel = (d == 0) ? p.bel0 : ((d == 1) ? p.bel1 : p.bel2);
    int N = (d == 1) ? 3072 : 1536;
    int lo = 0, hi = N;
    while (lo < hi) { int m = (lo + hi) / 2; if (bel[m] < b) lo = m + 1; else hi = m; }
    int st = lo; hi = N;
    while (lo < hi) { int m = (lo + hi) / 2; if (bel[m] < b + 1) lo = m + 1; else hi = m; }
    s_rng[t * 2] = st;
    s_rng[t * 2 + 1] = lo;
  }
  __syncthreads();
  int dt = s_dt;
  if (dt == 0)      mega_body<0>(p, smem, s_rng);
  else if (dt == 1) mega_body<1>(p, smem, s_rng);
  else              mega_body<2>(p, smem, s_rng);
}

// ======================= fallback: verified 10-kernel path =======================
__global__ void ct67_init(const unsigned short* x0u, const int* b0, const int* b1,
                          const int* b2, int* ranges, int* flags) {
  int t = threadIdx.x;
  if (t == 63) {
    float vals[32], mean = 0.f, var = 0.f;
    for (int i = 0; i < 32; i++) {
      union { unsigned int u; float f; } c;
      c.u = ((unsigned int)x0u[i]) << 16;
      vals[i] = c.f; mean += c.f;
    }
    mean /= 32.f;
    for (int i = 0; i < 32; i++) var += (vals[i] - mean) * (vals[i] - mean);
    var /= 32.f;
    flags[0] = (var < 1e-6f) ? 1 : ((var < 1e3f) ? 0 : 2);
  }
  if (t < 24) {
    int d = t / 8, b = t % 8;
    const int* bel = (d == 0) ? b0 : ((d == 1) ? b1 : b2);
    int N = (d == 1) ? 3072 : 1536;
    int lo = 0, hi = N;
    while (lo < hi) { int m = (lo + hi) / 2; if (bel[m] < b) lo = m + 1; else hi = m; }
    int st = lo; hi = N;
    while (lo < hi) { int m = (lo + hi) / 2; if (bel[m] < b + 1) lo = m + 1; else hi = m; }
    ranges[t * 2] = st;
    ranges[t * 2 + 1] = lo;
  }
}

template <int DT>
__device__ void ellem_body(const void* adj00, const void* b01, const void* adj11,
                           const void* b12, const void* adj22,
                           const int* bel0, const int* bel1, const int* bel2,
                           const int* ranges, int* ell, int* nnz,
                           const void* x0, const void* pe0, const void* wf0,
                           const void* bf0, const void* wp0, const void* x1,
                           const void* pe1, const void* wf1, const void* bf1,
                           const void* wp1, const void* x2, const void* pe2,
                           const void* wf2, const void* bf2, const void* wp2,
                           float* hout) {
  int tid = threadIdx.x;
  int lane = tid % 64, wid = tid / 64;
  if (blockIdx.x < 3840) {
    const int sdv[7] = {0, 0, 1, 1, 1, 2, 2};
    const int tdv[7] = {0, 1, 0, 1, 2, 1, 2};
    int bi = blockIdx.x * 4 + wid;
    int i, t;
    ct67_itab(bi, i, t);
    const void* mp; long mts, mss;
    ct67_mask<DT>(i, adj00, b01, adj11, b12, adj22, mp, mts, mss);
    const int* belt = (tdv[i] == 0) ? bel0 : ((tdv[i] == 1) ? bel1 : bel2);
    int b = belt[t];
    if (b < 0) b = 0;
    if (b > 7) b = 7;
    const int* rng = ranges + sdv[i] * 16;
    int s0 = rng[b * 2], s1 = rng[b * 2 + 1];
    int base = 0;
    for (int s = s0; s < s1; s += 64) {
      int ss = s + lane;
      bool pred = false;
      if (ss < s1) pred = msknzT<DT>(mp, (long)t * mts + (long)ss * mss);
      unsigned long long bal = __ballot(pred);
      int pos = __popcll(bal & ((1ull << lane) - 1ull));
      if (pred && base + pos < 128) ell[(long)bi * 128 + base + pos] = ss;
      base += __popcll(bal);
    }
    if (lane == 0) nnz[bi] = base;
  } else {
    int row = (blockIdx.x - 3840) * 4 + wid;
    int d = (row < 1536) ? 0 : ((row < 4608) ? 1 : 2);
    int r = row - ((d == 0) ? 0 : ((d == 1) ? 1536 : 4608));
    const void* x  = (d == 0) ? x0  : ((d == 1) ? x1  : x2);
    const void* pe = (d == 0) ? pe0 : ((d == 1) ? pe1 : pe2);
    const void* wf = (d == 0) ? wf0 : ((d == 1) ? wf1 : wf2);
    const void* bf = (d == 0) ? bf0 : ((d == 1) ? bf1 : bf2);
    const void* wp = (d == 0) ? wp0 : ((d == 1) ? wp1 : wp2);
    float acc = ldT<DT>(bf, lane);
#pragma unroll 8
    for (int f = 0; f < 32; f++)
      acc += ldT<DT>(x, (long)r * 32 + f) * ldT<DT>(wf, f * 64 + lane);
#pragma unroll 8
    for (int q = 0; q < 16; q++)
      acc += ldT<DT>(pe, (long)r * 16 + q) * ldT<DT>(wp, q * 64 + lane);
    hout[(long)row * 64 + lane] = acc;
  }
}
__global__ void ct67_ellem(const void* adj00, const void* b01, const void* adj11,
                           const void* b12, const void* adj22,
                           const int* bel0, const int* bel1, const int* bel2,
                           const int* ranges, int* ell, int* nnz,
                           const void* x0, const void* pe0, const void* wf0,
                           const void* bf0, const void* wp0, const void* x1,
                           const void* pe1, const void* wf1, const void* bf1,
                           const void* wp1, const void* x2, const void* pe2,
                           const void* wf2, const void* bf2, const void* wp2,
                           float* hout, const int* dtp) {
  int dt = dtp[0];
  if (dt == 0)
    ellem_body<0>(adj00,b01,adj11,b12,adj22,bel0,bel1,bel2,ranges,ell,nnz,
                  x0,pe0,wf0,bf0,wp0,x1,pe1,wf1,bf1,wp1,x2,pe2,wf2,bf2,wp2,hout);
  else if (dt == 1)
    ellem_body<1>(adj00,b01,adj11,b12,adj22,bel0,bel1,bel2,ranges,ell,nnz,
                  x0,pe0,wf0,bf0,wp0,x1,pe1,wf1,bf1,wp1,x2,pe2,wf2,bf2,wp2,hout);
  else
    ellem_body<2>(adj00,b01,adj11,b12,adj22,bel0,bel1,bel2,ranges,ell,nnz,
                  x0,pe0,wf0,bf0,wp0,x1,pe1,wf1,bf1,wp1,x2,pe2,wf2,bf2,wp2,hout);
}

template <int DT>
__device__ void qkv_body(const float* h, const void* Wq, const void* bq, const void* Wk,
                         const void* bk, const void* Wv, const void* bv,
                         float* qd, float* kd, float* vd, int l) {
  const int segend[21] = {1536, 3072, 4608, 7680, 9216, 10752, 12288, 15360, 18432,
                          21504, 24576, 27648, 29184, 32256, 35328, 38400, 39936,
                          41472, 43008, 44544, 46080};
  const int segsrc[21] = {0, 0, 0, 1, 0, 0, 0, 1, 1, 1, 1, 1, 2, 1, 1, 1, 2, 2, 2, 2, 2};
  const int segdst[21] = {0, 0, 0, 1536, 1536, 1536, 4608, 3072, 3072, 6144, 6144, 6144,
                          9216, 9216, 9216, 10752, 12288, 12288, 13824, 13824, 13824};
  const int rowoff[3] = {0, 1536, 4608};
  __shared__ float sW[4096];
  int tid = threadIdx.x;
  int lane = tid & 63;
  int wid = tid >> 6;
  int gbase = blockIdx.x * 64;
  int seg = 0;
  while (gbase >= segend[seg]) seg++;
  int segstart = (seg == 0) ? 0 : segend[seg - 1];
  int i = seg / 3, role = seg - i * 3;
  const void* W = (role == 0) ? Wq : (role == 1) ? Wk : Wv;
  const void* bbp = (role == 0) ? bq : (role == 1) ? bk : bv;
  long wbase = (long)(l * 7 + i) * 4096;
#pragma unroll
  for (int kkk = 0; kkk < 8; kkk++) {
    int idx = tid + kkk * 512;
    sW[idx] = ldT<DT>(W, wbase + idx);
  }
  int rbase = gbase - segstart + wid * 8;
  int hrow0 = rowoff[segsrc[seg]] + rbase;
  float hreg[8];
#pragma unroll
  for (int rr = 0; rr < 8; rr++) hreg[rr] = h[(long)(hrow0 + rr) * 64 + lane];
  __syncthreads();
  float bias = ldT<DT>(bbp, (long)(l * 7 + i) * 64 + lane);
  float acc[8];
#pragma unroll
  for (int rr = 0; rr < 8; rr++) acc[rr] = bias;
#pragma unroll 8
  for (int kk = 0; kk < 64; kk++) {
    float wv = sW[kk * 64 + lane];
#pragma unroll
    for (int rr = 0; rr < 8; rr++)
      acc[rr] += bcastlane(hreg[rr], kk) * wv;
  }
  float* dst = (role == 0) ? qd : (role == 1) ? kd : vd;
#pragma unroll
  for (int rr = 0; rr < 8; rr++)
    dst[(long)(segdst[seg] + rbase + rr) * 64 + lane] = acc[rr];
}
__global__ void ct67_qkv(const float* h, const void* Wq, const void* bq, const void* Wk,
                         const void* bk, const void* Wv, const void* bv,
                         float* qd, float* kd, float* vd, int l, const int* dtp) {
  int dt = dtp[0];
  if (dt == 0)      qkv_body<0>(h, Wq, bq, Wk, bk, Wv, bv, qd, kd, vd, l);
  else if (dt == 1) qkv_body<1>(h, Wq, bq, Wk, bk, Wv, bv, qd, kd, vd, l);
  else              qkv_body<2>(h, Wq, bq, Wk, bk, Wv, bv, qd, kd, vd, l);
}

template <int DT>
__device__ void attn_body(const float* qb, const float* kb, const float* vb,
                          const void* Wo, const void* bo,
                          const void* adj00, const void* b01, const void* adj11,
                          const void* b12, const void* adj22,
                          const int* bel0, const int* bel1, const int* bel2,
                          const int* ranges, const int* ell, const int* nnz, int ellok,
                          float* obuf, int l) {
  const int koff[7] = {0, 1536, 3072, 6144, 9216, 12288, 13824};
  const int sdv[7] = {0, 0, 1, 1, 1, 2, 2};
  const int tdv[7] = {0, 1, 0, 1, 2, 1, 2};
  __shared__ float sWo[4096];
  int tid = threadIdx.x;
  int lane = tid & 63;
  int wid = tid >> 6;
  int bi = blockIdx.x * 4 + wid;
  int i0, t0;
  ct67_itab(blockIdx.x * 4, i0, t0);
  long wobase = (long)(l * 7 + i0) * 4096;
  for (int idx = tid; idx < 4096; idx += 256) sWo[idx] = ldT<DT>(Wo, wobase + idx);
  int i, t;
  ct67_itab(bi, i, t);
  int hh = lane / 8, jj = lane % 8;
  const float4* qp = (const float4*)(qb + (long)bi * 64 + hh * 8);
  float4 q0 = qp[0], q1 = qp[1];
  const float* kbase = kb + (long)koff[i] * 64 + hh * 8;
  const float* vbase = vb + (long)koff[i] * 64 + hh * 8;
  float mr = -1e30f, lr = 0.f, o[8];
#pragma unroll
  for (int d = 0; d < 8; d++) o[d] = 0.f;
  int n = ellok ? nnz[bi] : 129;
  if (n <= 128) {
    const int* hl = ell + (long)bi * 128;
    for (int hidx = jj; hidx < n; hidx += 8) {
      int s = hl[hidx];
      const float4* kp = (const float4*)(kbase + (long)s * 64);
      float4 k0 = kp[0], k1 = kp[1];
      float sc = q0.x * k0.x + q0.y * k0.y + q0.z * k0.z + q0.w * k0.w +
                 q1.x * k1.x + q1.y * k1.y + q1.z * k1.z + q1.w * k1.w;
      sc *= 0.35355339059327373f;
      float nm = fmaxf(mr, sc);
      float fo = expf(mr - nm);
      float wv = expf(sc - nm);
      lr = lr * fo + wv;
      const float4* vp = (const float4*)(vbase + (long)s * 64);
      float4 v0 = vp[0], v1 = vp[1];
      o[0] = o[0] * fo + wv * v0.x; o[1] = o[1] * fo + wv * v0.y;
      o[2] = o[2] * fo + wv * v0.z; o[3] = o[3] * fo + wv * v0.w;
      o[4] = o[4] * fo + wv * v1.x; o[5] = o[5] * fo + wv * v1.y;
      o[6] = o[6] * fo + wv * v1.z; o[7] = o[7] * fo + wv * v1.w;
      mr = nm;
    }
  } else {
    const void* mp; long mts, mss;
    ct67_mask<DT>(i, adj00, b01, adj11, b12, adj22, mp, mts, mss);
    const int* belt = (tdv[i] == 0) ? bel0 : ((tdv[i] == 1) ? bel1 : bel2);
    int b = belt[t];
    if (b < 0) b = 0;
    if (b > 7) b = 7;
    const int* rng = ranges + sdv[i] * 16;
    int s0 = rng[b * 2], s1 = rng[b * 2 + 1];
    for (int s = s0 + jj; s < s1; s += 8) {
      if (msknzT<DT>(mp, (long)t * mts + (long)s * mss)) {
        const float4* kp = (const float4*)(kbase + (long)s * 64);
        float4 k0 = kp[0], k1 = kp[1];
        float sc = q0.x * k0.x + q0.y * k0.y + q0.z * k0.z + q0.w * k0.w +
                   q1.x * k1.x + q1.y * k1.y + q1.z * k1.z + q1.w * k1.w;
        sc *= 0.35355339059327373f;
        float nm = fmaxf(mr, sc);
        float fo = expf(mr - nm);
        float wv = expf(sc - nm);
        lr = lr * fo + wv;
        const float4* vp = (const float4*)(vbase + (long)s * 64);
        float4 v0 = vp[0], v1 = vp[1];
        o[0] = o[0] * fo + wv * v0.x; o[1] = o[1] * fo + wv * v0.y;
        o[2] = o[2] * fo + wv * v0.z; o[3] = o[3] * fo + wv * v0.w;
        o[4] = o[4] * fo + wv * v1.x; o[5] = o[5] * fo + wv * v1.y;
        o[6] = o[6] * fo + wv * v1.z; o[7] = o[7] * fo + wv * v1.w;
        mr = nm;
      }
    }
  }
#pragma unroll
  for (int off = 1; off < 8; off <<= 1) {
    float m2 = __shfl_xor(mr, off, 64);
    float l2 = __shfl_xor(lr, off, 64);
    float nm = fmaxf(mr, m2);
    float f1 = expf(mr - nm), f2 = expf(m2 - nm);
    lr = lr * f1 + l2 * f2;
#pragma unroll
    for (int d = 0; d < 8; d++) {
      float o2 = __shfl_xor(o[d], off, 64);
      o[d] = o[d] * f1 + o2 * f2;
    }
    mr = nm;
  }
  float val[8];
#pragma unroll
  for (int d = 0; d < 8; d++) val[d] = (lr > 0.f) ? (o[d] / lr) : 0.f;
  __syncthreads();
  float acc = ldT<DT>(bo, (long)(l * 7 + i) * 64 + lane);
  for (int g = 0; g < 8; g++) {
#pragma unroll
    for (int e = 0; e < 8; e++) {
      float sv = bcastlane(val[e], g * 8);
      acc += sv * sWo[(g * 8 + e) * 64 + lane];
    }
  }
  obuf[(long)bi * 64 + lane] = acc;
}
__global__ void ct67_attn(
    const float* qb, const float* kb, const float* vb, const void* Wo, const void* bo,
    const void* adj00, const void* b01, const void* adj11, const void* b12,
    const void* adj22, const int* bel0, const int* bel1, const int* bel2,
    const int* ranges, const int* ell, const int* nnz, int ellok,
    float* obuf, int l, const int* dtp) {
  int dt = dtp[0];
  if (dt == 0)
    attn_body<0>(qb,kb,vb,Wo,bo,adj00,b01,adj11,b12,adj22,bel0,bel1,bel2,ranges,ell,nnz,ellok,obuf,l);
  else if (dt == 1)
    attn_body<1>(qb,kb,vb,Wo,bo,adj00,b01,adj11,b12,adj22,bel0,bel1,bel2,ranges,ell,nnz,ellok,obuf,l);
  else
    attn_body<2>(qb,kb,vb,Wo,bo,adj00,b01,adj11,b12,adj22,bel0,bel1,bel2,ranges,ell,nnz,ellok,obuf,l);
}

template <int DT>
__device__ void ffn_body(const float* h, const float* obuf, float* hout,
                         const void* W1, const void* b1, const void* W2, const void* b2,
                         const void* g1, const void* be1, const void* g2, const void* be2,
                         int l) {
  __shared__ float sh[8][64];
  __shared__ float sf[8][256];
  __shared__ float sp[4][8][64];
  int tid = threadIdx.x;
  int lane = tid & 63;
  int wid = tid >> 6;
  int row0 = blockIdx.x * 8;
  int d = (row0 < 1536) ? 0 : ((row0 < 4608) ? 1 : 2);
  long gb = (long)(l * 3 + d) * 64;
  for (int rr = 0; rr < 2; rr++) {
    int r = wid * 2 + rr;
    int row = row0 + r;
    float x = h[(long)row * 64 + lane];
    if (d == 0) {
      int rw = row;
      x += obuf[(long)rw * 64 + lane] + obuf[(long)(4608 + rw) * 64 + lane];
    } else if (d == 1) {
      int rw = row - 1536;
      x += obuf[(long)(1536 + rw) * 64 + lane] + obuf[(long)(6144 + rw) * 64 + lane] +
           obuf[(long)(10752 + rw) * 64 + lane];
    } else {
      int rw = row - 4608;
      x += obuf[(long)(9216 + rw) * 64 + lane] + obuf[(long)(13824 + rw) * 64 + lane];
    }
    float mu = wred64(x) * 0.015625f;
    float dx = x - mu;
    float var = wred64(dx * dx) * 0.015625f;
    sh[r][lane] = dx * rsqrtf(var + 1e-5f) * ldT<DT>(g1, gb + lane) + ldT<DT>(be1, gb + lane);
  }
  __syncthreads();
  float hreg[8];
#pragma unroll
  for (int r = 0; r < 8; r++) hreg[r] = sh[r][lane];
  long wb1 = (long)(l * 3 + d) * 16384;
  float bb1 = ldT<DT>(b1, (long)(l * 3 + d) * 256 + tid);
  float acc1[8];
#pragma unroll
  for (int r = 0; r < 8; r++) acc1[r] = bb1;
#pragma unroll 8
  for (int kk = 0; kk < 64; kk++) {
    float wv = ldT<DT>(W1, wb1 + kk * 256 + tid);
#pragma unroll
    for (int r = 0; r < 8; r++) acc1[r] += bcastlane(hreg[r], kk) * wv;
  }
#pragma unroll
  for (int r = 0; r < 8; r++) sf[r][tid] = fmaxf(acc1[r], 0.f);
  __syncthreads();
  int k0 = wid * 64;
  float sreg[8];
#pragma unroll
  for (int r = 0; r < 8; r++) sreg[r] = sf[r][k0 + lane];
  long wb2 = (long)(l * 3 + d) * 16384;
  float a2[8];
#pragma unroll
  for (int r = 0; r < 8; r++) a2[r] = 0.f;
#pragma unroll 8
  for (int kk = 0; kk < 64; kk++) {
    float w2 = ldT<DT>(W2, wb2 + (long)(k0 + kk) * 64 + lane);
#pragma unroll
    for (int r = 0; r < 8; r++) a2[r] += bcastlane(sreg[r], kk) * w2;
  }
#pragma unroll
  for (int r = 0; r < 8; r++) sp[wid][r][lane] = a2[r];
  __syncthreads();
  for (int rr = 0; rr < 2; rr++) {
    int r = wid * 2 + rr;
    int row = row0 + r;
    float x = sh[r][lane] + ldT<DT>(b2, gb + lane) +
              sp[0][r][lane] + sp[1][r][lane] + sp[2][r][lane] + sp[3][r][lane];
    float mu = wred64(x) * 0.015625f;
    float dx = x - mu;
    float var = wred64(dx * dx) * 0.015625f;
    hout[(long)row * 64 + lane] =
        dx * rsqrtf(var + 1e-5f) * ldT<DT>(g2, gb + lane) + ldT<DT>(be2, gb + lane);
  }
}
__global__ void ct67_ffn(const float* h, const float* obuf, float* hout,
                         const void* W1, const void* b1, const void* W2, const void* b2,
                         const void* g1, const void* be1, const void* g2, const void* be2,
                         int l, const int* dtp) {
  int dt = dtp[0];
  if (dt == 0)      ffn_body<0>(h, obuf, hout, W1, b1, W2, b2, g1, be1, g2, be2, l);
  else if (dt == 1) ffn_body<1>(h, obuf, hout, W1, b1, W2, b2, g1, be1, g2, be2, l);
  else              ffn_body<2>(h, obuf, hout, W1, b1, W2, b2, g1, be1, g2, be2, l);
}

__global__ void ct67_poolp(const float* h, const int* ranges, float* ppart) {
  int b = blockIdx.x;
  int c = blockIdx.y;
  int j = threadIdx.x;
  float s = 0.f;
  for (int d = 0; d < 3; d++) {
    int st = ranges[(d * 8 + b) * 2], en = ranges[(d * 8 + b) * 2 + 1];
    int ro = (d == 0) ? 0 : ((d == 1) ? 1536 : 4608);
    for (int r = st + c; r < en; r += 32) s += h[(long)(ro + r) * 64 + j];
  }
  ppart[(long)(b * 32 + c) * 64 + j] = s;
}

template <int DT>
__device__ void poolmlp_body(const float* ppart, const int* ranges,
                             const void* Wh1, const void* bh1, const void* Wh2,
                             const void* bh2, const void* Wh3, const void* bh3,
                             float* out) {
  __shared__ float pooled[8][64];
  __shared__ float y1[8][64];
  __shared__ float y2[8][64];
  int tid = threadIdx.x;
  int b = tid / 64, j = tid % 64;
  float s = 0.f;
  for (int c = 0; c < 32; c++) s += ppart[(long)(b * 32 + c) * 64 + j];
  int cnt = 0;
  for (int d = 0; d < 3; d++)
    cnt += ranges[(d * 8 + b) * 2 + 1] - ranges[(d * 8 + b) * 2];
  pooled[b][j] = (cnt > 0) ? (s / (float)cnt) : 0.f;
  __syncthreads();
  float acc = ldT<DT>(bh1, j);
  for (int kk = 0; kk < 64; kk++) acc += pooled[b][kk] * ldT<DT>(Wh1, kk * 64 + j);
  y1[b][j] = fmaxf(acc, 0.f);
  __syncthreads();
  acc = ldT<DT>(bh2, j);
  for (int kk = 0; kk < 64; kk++) acc += y1[b][kk] * ldT<DT>(Wh2, kk * 64 + j);
  y2[b][j] = fmaxf(acc, 0.f);
  __syncthreads();
  if (j < 10) {
    float o = ldT<DT>(bh3, j);
    for (int kk = 0; kk < 64; kk++) o += y2[b][kk] * ldT<DT>(Wh3, kk * 10 + j);
    out[b * 10 + j] = o;
  }
}
__global__ void ct67_poolmlp(const float* ppart, const int* ranges,
                             const void* Wh1, const void* bh1, const void* Wh2,
                             const void* bh2, const void* Wh3, const void* bh3,
                             float* out, const int* dtp) {
  int dt = dtp[0];
  if (dt == 0)      poolmlp_body<0>(ppart, ranges, Wh1, bh1, Wh2, bh2, Wh3, bh3, out);
  else if (dt == 1) poolmlp_body<1>(ppart, ranges, Wh1, bh1, Wh2, bh2, Wh3, bh3, out);
  else              poolmlp_body<2>(ppart, ranges, Wh1, bh1, Wh2, bh2, Wh3, bh3, out);
}

extern "C" void kernel_launch(void* const* d_in, const int* in_sizes, int n_in,
                              void* d_out, int out_size, void* d_ws, size_t ws_size,
                              hipStream_t stream) {
  (void)in_sizes; (void)n_in; (void)out_size;
  const void* x0 = d_in[0];  const void* pe0 = d_in[1];  const int* bel0 = (const int*)d_in[2];
  const void* x1 = d_in[3];  const void* pe1 = d_in[4];  const int* bel1 = (const int*)d_in[5];
  const void* x2 = d_in[6];  const void* pe2 = d_in[7];  const int* bel2 = (const int*)d_in[8];
  const void* adj00 = d_in[9];  const void* adj11 = d_in[10]; const void* adj22 = d_in[11];
  const void* b01 = d_in[12];   const void* b12 = d_in[13];
  const void* Wf0 = d_in[14]; const void* bf0 = d_in[15]; const void* Wp0 = d_in[16];
  const void* Wf1 = d_in[17]; const void* bf1 = d_in[18]; const void* Wp1 = d_in[19];
  const void* Wf2 = d_in[20]; const void* bf2 = d_in[21]; const void* Wp2 = d_in[22];
  const void* Wq = d_in[23]; const void* bq = d_in[24];
  const void* Wk = d_in[25]; const void* bk = d_in[26];
  const void* Wv = d_in[27]; const void* bv = d_in[28];
  const void* Wo = d_in[29]; const void* bo = d_in[30];
  const void* g1 = d_in[31]; const void* be1 = d_in[32];
  const void* g2 = d_in[33]; const void* be2 = d_in[34];
  const void* Wff1 = d_in[35]; const void* bff1 = d_in[36];
  const void* Wff2 = d_in[37]; const void* bff2 = d_in[38];
  const void* Wh1 = d_in[39]; const void* bh1 = d_in[40];
  const void* Wh2 = d_in[41]; const void* bh2 = d_in[42];
  const void* Wh3 = d_in[43]; const void* bh3 = d_in[44];

  char* w = (char*)d_ws;
  float* hbuf   = (float*)(w + 0);          // 1572864
  float* obuf   = (float*)(w + 1572864);    // -> 5505024
  float* qb     = (float*)(w + 5505024);    // -> 9437184
  float* kb     = (float*)(w + 9437184);    // -> 13369344
  float* vb     = (float*)(w + 13369344);   // -> 17301504
  int* ranges   = (int*)(w + 17301504);     // -> 17301696
  int* flags    = (int*)(w + 17301696);     // -> 17301760
  float* ppart  = (float*)(w + 17301760);   // -> 17367296
  int* ell      = (int*)(w + 17367296);     // -> 25231616
  int* nnz      = (int*)(w + 25231616);     // -> 25293056
  int ellok = (ws_size >= (size_t)25293056) ? 1 : 0;

  CTP p;
  p.x0 = x0; p.pe0 = pe0; p.bel0 = bel0;
  p.x1 = x1; p.pe1 = pe1; p.bel1 = bel1;
  p.x2 = x2; p.pe2 = pe2; p.bel2 = bel2;
  p.adj00 = adj00; p.adj11 = adj11; p.adj22 = adj22; p.b01 = b01; p.b12 = b12;
  p.Wf0 = Wf0; p.bf0 = bf0; p.Wp0 = Wp0;
  p.Wf1 = Wf1; p.bf1 = bf1; p.Wp1 = Wp1;
  p.Wf2 = Wf2; p.bf2 = bf2; p.Wp2 = Wp2;
  p.Wq = Wq; p.bq = bq; p.Wk = Wk; p.bk = bk; p.Wv = Wv; p.bv = bv; p.Wo = Wo; p.bo = bo;
  p.g1 = g1; p.be1 = be1; p.g2 = g2; p.be2 = be2;
  p.Wff1 = Wff1; p.bff1 = bff1; p.Wff2 = Wff2; p.bff2 = bff2;
  p.Wh1 = Wh1; p.bh1 = bh1; p.Wh2 = Wh2; p.bh2 = bh2; p.Wh3 = Wh3; p.bh3 = bh3;
  p.hbuf = hbuf; p.obuf = obuf; p.qb = qb; p.kb = kb; p.vb = vb; p.ppart = ppart;
  p.ell = ell; p.nnz = nnz;
  p.out = (float*)d_out;
  p.ellok = ellok;

  void* args[] = { &p };
  hipError_t err = hipLaunchCooperativeKernel(
      reinterpret_cast<const void*>(&CellularTransformer_67345087201410_kernel),
      dim3(512), dim3(256), args, 0, stream);
  if (err != hipSuccess) {
    // fallback: verified 10-kernel pipeline
    ct67_init<<<1, 64, 0, stream>>>((const unsigned short*)x0, bel0, bel1, bel2, ranges, flags);
    ct67_ellem<<<5376, 256, 0, stream>>>(adj00, b01, adj11, b12, adj22,
                                         bel0, bel1, bel2, ranges, ell, nnz,
                                         x0, pe0, Wf0, bf0, Wp0, x1, pe1, Wf1, bf1, Wp1,
                                         x2, pe2, Wf2, bf2, Wp2, hbuf, flags);
    for (int l = 0; l < 2; l++) {
      ct67_qkv<<<720, 512, 0, stream>>>(hbuf, Wq, bq, Wk, bk, Wv, bv, qb, kb, vb, l, flags);
      ct67_attn<<<3840, 256, 0, stream>>>(
          qb, kb, vb, Wo, bo, adj00, b01, adj11, b12, adj22,
          bel0, bel1, bel2, ranges, ell, nnz, ellok, obuf, l, flags);
      ct67_ffn<<<768, 256, 0, stream>>>(hbuf, obuf, hbuf, Wff1, bff1, Wff2, bff2,
                                        g1, be1, g2, be2, l, flags);
    }
    ct67_poolp<<<dim3(8, 32), 64, 0, stream>>>(hbuf, ranges, ppart);
    ct67_poolmlp<<<1, 512, 0, stream>>>(ppart, ranges, Wh1, bh1, Wh2, bh2, Wh3, bh3,
                                        (float*)d_out, flags);
  }
}

// Round 3
// 570.228 us; speedup vs baseline: 1.5680x; 1.5680x over previous
//
#include <hip/hip_runtime.h>
#include <hip/hip_bf16.h>
#include <hip/hip_fp16.h>

// Storage-dtype-templated load: DT=0 bf16, DT=1 fp16, DT=2 f32.
template <int DT>
__device__ __forceinline__ float ldT(const void* p, long i) {
  if (DT == 0) {
    unsigned int a = ((unsigned int)((const unsigned short*)p)[i]) << 16;
    union { unsigned int u; float f; } c; c.u = a; return c.f;
  } else if (DT == 1) {
    return __half2float(((const __half*)p)[i]);
  } else {
    return ((const float*)p)[i];
  }
}
template <int DT>
__device__ __forceinline__ bool msknzT(const void* p, long i) {
  if (DT < 2) return ((const unsigned short*)p)[i] != 0;  // 0.0 encodes as 0x0000
  return ((const float*)p)[i] != 0.f;
}
__device__ __forceinline__ float wred64(float v) {
#pragma unroll
  for (int off = 1; off < 64; off <<= 1) v += __shfl_xor(v, off, 64);
  return v;
}
// wave-uniform broadcast of lane l's value (v_readlane -> SGPR operand)
__device__ __forceinline__ float bcastlane(float v, int l) {
  return __int_as_float(__builtin_amdgcn_readlane(__float_as_int(v), l));
}
__device__ __forceinline__ void ct67_itab(int bi, int& i, int& t) {
  const int toff[8] = {0, 1536, 4608, 6144, 9216, 10752, 13824, 15360};
  i = 0;
  while (bi >= toff[i + 1]) i++;
  t = bi - toff[i];
}
template <int DT>
__device__ __forceinline__ void ct67_mask(int i, const void* adj00, const void* b01,
                                          const void* adj11, const void* b12,
                                          const void* adj22, const void*& mp,
                                          long& mts, long& mss) {
  switch (i) {
    case 0: mp = adj00; mts = 1536; mss = 1; break;
    case 1: mp = b01;   mts = 1;    mss = 3072; break;
    case 2: mp = b01;   mts = 3072; mss = 1; break;
    case 3: mp = adj11; mts = 3072; mss = 1; break;
    case 4: mp = b12;   mts = 1;    mss = 1536; break;
    case 5: mp = b12;   mts = 1536; mss = 1; break;
    default: mp = adj22; mts = 1536; mss = 1; break;
  }
}

// ---------------- init: dtype classify + batch ranges ----------------
__global__ void ct67_init(const unsigned short* x0u, const int* b0, const int* b1,
                          const int* b2, int* ranges, int* flags) {
  int t = threadIdx.x;
  if (t == 63) {
    float vals[32], mean = 0.f, var = 0.f;
    for (int i = 0; i < 32; i++) {
      union { unsigned int u; float f; } c;
      c.u = ((unsigned int)x0u[i]) << 16;
      vals[i] = c.f; mean += c.f;
    }
    mean /= 32.f;
    for (int i = 0; i < 32; i++) var += (vals[i] - mean) * (vals[i] - mean);
    var /= 32.f;
    flags[0] = (var < 1e-6f) ? 1 : ((var < 1e3f) ? 0 : 2);
  }
  if (t < 24) {
    int d = t / 8, b = t % 8;
    const int* bel = (d == 0) ? b0 : ((d == 1) ? b1 : b2);
    int N = (d == 1) ? 3072 : 1536;
    int lo = 0, hi = N;
    while (lo < hi) { int m = (lo + hi) / 2; if (bel[m] < b) lo = m + 1; else hi = m; }
    int st = lo; hi = N;
    while (lo < hi) { int m = (lo + hi) / 2; if (bel[m] < b + 1) lo = m + 1; else hi = m; }
    ranges[t * 2] = st;
    ranges[t * 2 + 1] = lo;
  }
}

// ---------------- merged ELL-build + embed (independent stages, one launch) ------
// blocks [0,2688): row-major ELL rows (ballot scan, coalesced), 4 waves x 1 row.
// blocks [2688,2706): transposed ELL (i=1,4): 1 wave owns 64 target columns and
//   iterates source rows serially -> every mask load is one coalesced 128B line;
//   each lane appends to its own ELL row (same membership/order -> bit-exact).
// blocks [2706,4242): embed, 4 rows/block.
template <int DT>
__device__ void ellem_body(const void* adj00, const void* b01, const void* adj11,
                           const void* b12, const void* adj22,
                           const int* bel0, const int* bel1, const int* bel2,
                           const int* ranges, int* ell, int* nnz,
                           const void* x0, const void* pe0, const void* wf0,
                           const void* bf0, const void* wp0, const void* x1,
                           const void* pe1, const void* wf1, const void* bf1,
                           const void* wp1, const void* x2, const void* pe2,
                           const void* wf2, const void* bf2, const void* wp2,
                           float* hout) {
  int tid = threadIdx.x;
  int lane = tid % 64, wid = tid / 64;
  if (blockIdx.x < 2688) {
    // row-major interactions: i in {0,2,3,5,6} -> bi chunks [0,1536),[4608,9216),[10752,15360)
    const int sdv[7] = {0, 0, 1, 1, 1, 2, 2};
    const int tdv[7] = {0, 1, 0, 1, 2, 1, 2};
    int u = blockIdx.x * 4 + wid;  // 0..10751
    int bi = (u < 1536) ? u : ((u < 6144) ? u + 3072 : u + 4608);
    int i, t;
    ct67_itab(bi, i, t);
    const void* mp; long mts, mss;
    ct67_mask<DT>(i, adj00, b01, adj11, b12, adj22, mp, mts, mss);
    const int* belt = (tdv[i] == 0) ? bel0 : ((tdv[i] == 1) ? bel1 : bel2);
    int b = belt[t];
    if (b < 0) b = 0;
    if (b > 7) b = 7;
    const int* rng = ranges + sdv[i] * 16;
    int s0 = rng[b * 2], s1 = rng[b * 2 + 1];
    int base = 0;
    for (int s = s0; s < s1; s += 64) {
      int ss = s + lane;
      bool pred = false;
      if (ss < s1) pred = msknzT<DT>(mp, (long)t * mts + (long)ss * mss);
      unsigned long long bal = __ballot(pred);
      int pos = __popcll(bal & ((1ull << lane) - 1ull));
      if (pred && base + pos < 128) ell[(long)bi * 128 + base + pos] = ss;
      base += __popcll(bal);
    }
    if (lane == 0) nnz[bi] = base;
  } else if (blockIdx.x < 2706) {
    // transposed interactions: i=1 (b01^T, 48 col-groups), i=4 (b12^T, 24 col-groups)
    int g = (blockIdx.x - 2688) * 4 + wid;  // 0..71
    const void* mp; long ncols; int bioff; const int* belt; const int* rng; int t0;
    if (g < 48) { mp = b01; ncols = 3072; bioff = 1536; belt = bel1; rng = ranges + 0;  t0 = g * 64; }
    else        { mp = b12; ncols = 1536; bioff = 9216; belt = bel2; rng = ranges + 16; t0 = (g - 48) * 64; }
    int t = t0 + lane;
    int b = belt[t];
    if (b < 0) b = 0;
    if (b > 7) b = 7;
    int s0 = rng[b * 2], s1 = rng[b * 2 + 1];
    int smin = s0, smax = s1;
#pragma unroll
    for (int off = 1; off < 64; off <<= 1) {
      smin = min(smin, __shfl_xor(smin, off, 64));
      smax = max(smax, __shfl_xor(smax, off, 64));
    }
    int bi = bioff + t;
    int* pe = ell + (long)bi * 128;
    int cnt = 0;
    for (int ss = smin; ss < smax; ss++) {
      bool v = msknzT<DT>(mp, (long)ss * ncols + t);  // coalesced across lanes
      if (v && ss >= s0 && ss < s1) {
        if (cnt < 128) pe[cnt] = ss;
        cnt++;
      }
    }
    nnz[bi] = cnt;
  } else {
    int row = (blockIdx.x - 2706) * 4 + wid;
    int d = (row < 1536) ? 0 : ((row < 4608) ? 1 : 2);
    int r = row - ((d == 0) ? 0 : ((d == 1) ? 1536 : 4608));
    const void* x  = (d == 0) ? x0  : ((d == 1) ? x1  : x2);
    const void* pe = (d == 0) ? pe0 : ((d == 1) ? pe1 : pe2);
    const void* wf = (d == 0) ? wf0 : ((d == 1) ? wf1 : wf2);
    const void* bf = (d == 0) ? bf0 : ((d == 1) ? bf1 : bf2);
    const void* wp = (d == 0) ? wp0 : ((d == 1) ? wp1 : wp2);
    float acc = ldT<DT>(bf, lane);
#pragma unroll 8
    for (int f = 0; f < 32; f++)
      acc += ldT<DT>(x, (long)r * 32 + f) * ldT<DT>(wf, f * 64 + lane);
#pragma unroll 8
    for (int q = 0; q < 16; q++)
      acc += ldT<DT>(pe, (long)r * 16 + q) * ldT<DT>(wp, q * 64 + lane);
    hout[(long)row * 64 + lane] = acc;
  }
}
__global__ void ct67_ellem(const void* adj00, const void* b01, const void* adj11,
                           const void* b12, const void* adj22,
                           const int* bel0, const int* bel1, const int* bel2,
                           const int* ranges, int* ell, int* nnz,
                           const void* x0, const void* pe0, const void* wf0,
                           const void* bf0, const void* wp0, const void* x1,
                           const void* pe1, const void* wf1, const void* bf1,
                           const void* wp1, const void* x2, const void* pe2,
                           const void* wf2, const void* bf2, const void* wp2,
                           float* hout, const int* dtp) {
  int dt = dtp[0];
  if (dt == 0)
    ellem_body<0>(adj00,b01,adj11,b12,adj22,bel0,bel1,bel2,ranges,ell,nnz,
                  x0,pe0,wf0,bf0,wp0,x1,pe1,wf1,bf1,wp1,x2,pe2,wf2,bf2,wp2,hout);
  else if (dt == 1)
    ellem_body<1>(adj00,b01,adj11,b12,adj22,bel0,bel1,bel2,ranges,ell,nnz,
                  x0,pe0,wf0,bf0,wp0,x1,pe1,wf1,bf1,wp1,x2,pe2,wf2,bf2,wp2,hout);
  else
    ellem_body<2>(adj00,b01,adj11,b12,adj22,bel0,bel1,bel2,ranges,ell,nnz,
                  x0,pe0,wf0,bf0,wp0,x1,pe1,wf1,bf1,wp1,x2,pe2,wf2,bf2,wp2,hout);
}

// ---------------- qkv: 64 rows/block (8 waves x 8 rows, readlane broadcast) ------
template <int DT>
__device__ void qkv_body(const float* h, const void* Wq, const void* bq, const void* Wk,
                         const void* bk, const void* Wv, const void* bv,
                         float* qd, float* kd, float* vd, int l) {
  const int segend[21] = {1536, 3072, 4608, 7680, 9216, 10752, 12288, 15360, 18432,
                          21504, 24576, 27648, 29184, 32256, 35328, 38400, 39936,
                          41472, 43008, 44544, 46080};
  const int segsrc[21] = {0, 0, 0, 1, 0, 0, 0, 1, 1, 1, 1, 1, 2, 1, 1, 1, 2, 2, 2, 2, 2};
  const int segdst[21] = {0, 0, 0, 1536, 1536, 1536, 4608, 3072, 3072, 6144, 6144, 6144,
                          9216, 9216, 9216, 10752, 12288, 12288, 13824, 13824, 13824};
  const int rowoff[3] = {0, 1536, 4608};
  __shared__ float sW[4096];
  int tid = threadIdx.x;
  int lane = tid & 63;
  int wid = tid >> 6;
  int gbase = blockIdx.x * 64;
  int seg = 0;
  while (gbase >= segend[seg]) seg++;
  int segstart = (seg == 0) ? 0 : segend[seg - 1];
  int i = seg / 3, role = seg - i * 3;
  const void* W = (role == 0) ? Wq : (role == 1) ? Wk : Wv;
  const void* bbp = (role == 0) ? bq : (role == 1) ? bk : bv;
  long wbase = (long)(l * 7 + i) * 4096;
#pragma unroll
  for (int kkk = 0; kkk < 8; kkk++) {
    int idx = tid + kkk * 512;
    sW[idx] = ldT<DT>(W, wbase + idx);
  }
  int rbase = gbase - segstart + wid * 8;
  int hrow0 = rowoff[segsrc[seg]] + rbase;
  float hreg[8];
#pragma unroll
  for (int rr = 0; rr < 8; rr++) hreg[rr] = h[(long)(hrow0 + rr) * 64 + lane];
  __syncthreads();
  float bias = ldT<DT>(bbp, (long)(l * 7 + i) * 64 + lane);
  float acc[8];
#pragma unroll
  for (int rr = 0; rr < 8; rr++) acc[rr] = bias;
#pragma unroll 8
  for (int kk = 0; kk < 64; kk++) {
    float wv = sW[kk * 64 + lane];
#pragma unroll
    for (int rr = 0; rr < 8; rr++)
      acc[rr] += bcastlane(hreg[rr], kk) * wv;
  }
  float* dst = (role == 0) ? qd : (role == 1) ? kd : vd;
#pragma unroll
  for (int rr = 0; rr < 8; rr++)
    dst[(long)(segdst[seg] + rbase + rr) * 64 + lane] = acc[rr];
}
__global__ void ct67_qkv(const float* h, const void* Wq, const void* bq, const void* Wk,
                         const void* bk, const void* Wv, const void* bv,
                         float* qd, float* kd, float* vd, int l, const int* dtp) {
  int dt = dtp[0];
  if (dt == 0)      qkv_body<0>(h, Wq, bq, Wk, bk, Wv, bv, qd, kd, vd, l);
  else if (dt == 1) qkv_body<1>(h, Wq, bq, Wk, bk, Wv, bv, qd, kd, vd, l);
  else              qkv_body<2>(h, Wq, bq, Wk, bk, Wv, bv, qd, kd, vd, l);
}

// ---------------- attention + output projection: 8 rows/block, Wo staged in LDS --
template <int DT>
__device__ void attn_body(const float* qb, const float* kb, const float* vb,
                          const void* Wo, const void* bo,
                          const void* adj00, const void* b01, const void* adj11,
                          const void* b12, const void* adj22,
                          const int* bel0, const int* bel1, const int* bel2,
                          const int* ranges, const int* ell, const int* nnz, int ellok,
                          float* obuf, int l) {
  const int koff[7] = {0, 1536, 3072, 6144, 9216, 12288, 13824};
  const int sdv[7] = {0, 0, 1, 1, 1, 2, 2};
  const int tdv[7] = {0, 1, 0, 1, 2, 1, 2};
  __shared__ float sWo[4096];
  int tid = threadIdx.x;
  int lane = tid & 63;
  int wid = tid >> 6;
  int bi = blockIdx.x * 8 + wid;
  // all 8 rows of a block share one interaction i (i-boundaries are multiples of 8)
  int i0, t0;
  ct67_itab(blockIdx.x * 8, i0, t0);
  long wobase = (long)(l * 7 + i0) * 4096;
  for (int idx = tid; idx < 4096; idx += 512) sWo[idx] = ldT<DT>(Wo, wobase + idx);
  int i, t;
  ct67_itab(bi, i, t);
  int hh = lane / 8, jj = lane % 8;
  const float4* qp = (const float4*)(qb + (long)bi * 64 + hh * 8);
  float4 q0 = qp[0], q1 = qp[1];
  const float* kbase = kb + (long)koff[i] * 64 + hh * 8;
  const float* vbase = vb + (long)koff[i] * 64 + hh * 8;
  float mr = -1e30f, lr = 0.f, o[8];
#pragma unroll
  for (int d = 0; d < 8; d++) o[d] = 0.f;
  int n = ellok ? nnz[bi] : 129;
  if (n <= 128) {
    const int* hl = ell + (long)bi * 128;
    for (int hidx = jj; hidx < n; hidx += 8) {
      int s = hl[hidx];
      const float4* kp = (const float4*)(kbase + (long)s * 64);
      float4 k0 = kp[0], k1 = kp[1];
      float sc = q0.x * k0.x + q0.y * k0.y + q0.z * k0.z + q0.w * k0.w +
                 q1.x * k1.x + q1.y * k1.y + q1.z * k1.z + q1.w * k1.w;
      sc *= 0.35355339059327373f;
      float nm = fmaxf(mr, sc);
      float fo = expf(mr - nm);
      float wv = expf(sc - nm);
      lr = lr * fo + wv;
      const float4* vp = (const float4*)(vbase + (long)s * 64);
      float4 v0 = vp[0], v1 = vp[1];
      o[0] = o[0] * fo + wv * v0.x; o[1] = o[1] * fo + wv * v0.y;
      o[2] = o[2] * fo + wv * v0.z; o[3] = o[3] * fo + wv * v0.w;
      o[4] = o[4] * fo + wv * v1.x; o[5] = o[5] * fo + wv * v1.y;
      o[6] = o[6] * fo + wv * v1.z; o[7] = o[7] * fo + wv * v1.w;
      mr = nm;
    }
  } else {  // fallback: in-loop mask scan (overflow rows or no ELL workspace)
    const void* mp; long mts, mss;
    ct67_mask<DT>(i, adj00, b01, adj11, b12, adj22, mp, mts, mss);
    const int* belt = (tdv[i] == 0) ? bel0 : ((tdv[i] == 1) ? bel1 : bel2);
    int b = belt[t];
    if (b < 0) b = 0;
    if (b > 7) b = 7;
    const int* rng = ranges + sdv[i] * 16;
    int s0 = rng[b * 2], s1 = rng[b * 2 + 1];
    for (int s = s0 + jj; s < s1; s += 8) {
      if (msknzT<DT>(mp, (long)t * mts + (long)s * mss)) {
        const float4* kp = (const float4*)(kbase + (long)s * 64);
        float4 k0 = kp[0], k1 = kp[1];
        float sc = q0.x * k0.x + q0.y * k0.y + q0.z * k0.z + q0.w * k0.w +
                   q1.x * k1.x + q1.y * k1.y + q1.z * k1.z + q1.w * k1.w;
        sc *= 0.35355339059327373f;
        float nm = fmaxf(mr, sc);
        float fo = expf(mr - nm);
        float wv = expf(sc - nm);
        lr = lr * fo + wv;
        const float4* vp = (const float4*)(vbase + (long)s * 64);
        float4 v0 = vp[0], v1 = vp[1];
        o[0] = o[0] * fo + wv * v0.x; o[1] = o[1] * fo + wv * v0.y;
        o[2] = o[2] * fo + wv * v0.z; o[3] = o[3] * fo + wv * v0.w;
        o[4] = o[4] * fo + wv * v1.x; o[5] = o[5] * fo + wv * v1.y;
        o[6] = o[6] * fo + wv * v1.z; o[7] = o[7] * fo + wv * v1.w;
        mr = nm;
      }
    }
  }
  // merge 8 lanes per head via xor-butterfly (verified r13)
#pragma unroll
  for (int off = 1; off < 8; off <<= 1) {
    float m2 = __shfl_xor(mr, off, 64);
    float l2 = __shfl_xor(lr, off, 64);
    float nm = fmaxf(mr, m2);
    float f1 = expf(mr - nm), f2 = expf(m2 - nm);
    lr = lr * f1 + l2 * f2;
#pragma unroll
    for (int d = 0; d < 8; d++) {
      float o2 = __shfl_xor(o[d], off, 64);
      o[d] = o[d] * f1 + o2 * f2;
    }
    mr = nm;
  }
  float val[8];
#pragma unroll
  for (int d = 0; d < 8; d++) val[d] = (lr > 0.f) ? (o[d] / lr) : 0.f;
  __syncthreads();
  // Wo projection from LDS: readlane broadcast + FMA (same e/g order as before)
  float acc = ldT<DT>(bo, (long)(l * 7 + i) * 64 + lane);
  for (int g = 0; g < 8; g++) {
#pragma unroll
    for (int e = 0; e < 8; e++) {
      float sv = bcastlane(val[e], g * 8);
      acc += sv * sWo[(g * 8 + e) * 64 + lane];
    }
  }
  obuf[(long)bi * 64 + lane] = acc;
}
__global__ void CellularTransformer_67345087201410_kernel(
    const float* qb, const float* kb, const float* vb, const void* Wo, const void* bo,
    const void* adj00, const void* b01, const void* adj11, const void* b12,
    const void* adj22, const int* bel0, const int* bel1, const int* bel2,
    const int* ranges, const int* ell, const int* nnz, int ellok,
    float* obuf, int l, const int* dtp) {
  int dt = dtp[0];
  if (dt == 0)
    attn_body<0>(qb,kb,vb,Wo,bo,adj00,b01,adj11,b12,adj22,bel0,bel1,bel2,ranges,ell,nnz,ellok,obuf,l);
  else if (dt == 1)
    attn_body<1>(qb,kb,vb,Wo,bo,adj00,b01,adj11,b12,adj22,bel0,bel1,bel2,ranges,ell,nnz,ellok,obuf,l);
  else
    attn_body<2>(qb,kb,vb,Wo,bo,adj00,b01,adj11,b12,adj22,bel0,bel1,bel2,ranges,ell,nnz,ellok,obuf,l);
}

// ---------------- fused FFN: 8 rows/block, register-tiled FF1/FF2 ----------------
template <int DT>
__device__ void ffn_body(const float* h, const float* obuf, float* hout,
                         const void* W1, const void* b1, const void* W2, const void* b2,
                         const void* g1, const void* be1, const void* g2, const void* be2,
                         int l) {
  __shared__ float sh[8][64];
  __shared__ float sf[8][256];
  __shared__ float sp[4][8][64];
  int tid = threadIdx.x;
  int lane = tid & 63;
  int wid = tid >> 6;
  int row0 = blockIdx.x * 8;
  int d = (row0 < 1536) ? 0 : ((row0 < 4608) ? 1 : 2);
  long gb = (long)(l * 3 + d) * 64;
  for (int rr = 0; rr < 2; rr++) {
    int r = wid * 2 + rr;
    int row = row0 + r;
    float x = h[(long)row * 64 + lane];
    if (d == 0) {
      int rw = row;
      x += obuf[(long)rw * 64 + lane] + obuf[(long)(4608 + rw) * 64 + lane];
    } else if (d == 1) {
      int rw = row - 1536;
      x += obuf[(long)(1536 + rw) * 64 + lane] + obuf[(long)(6144 + rw) * 64 + lane] +
           obuf[(long)(10752 + rw) * 64 + lane];
    } else {
      int rw = row - 4608;
      x += obuf[(long)(9216 + rw) * 64 + lane] + obuf[(long)(13824 + rw) * 64 + lane];
    }
    float mu = wred64(x) * 0.015625f;
    float dx = x - mu;
    float var = wred64(dx * dx) * 0.015625f;
    sh[r][lane] = dx * rsqrtf(var + 1e-5f) * ldT<DT>(g1, gb + lane) + ldT<DT>(be1, gb + lane);
  }
  __syncthreads();
  float hreg[8];
#pragma unroll
  for (int r = 0; r < 8; r++) hreg[r] = sh[r][lane];
  long wb1 = (long)(l * 3 + d) * 16384;
  float bb1 = ldT<DT>(b1, (long)(l * 3 + d) * 256 + tid);
  float acc1[8];
#pragma unroll
  for (int r = 0; r < 8; r++) acc1[r] = bb1;
#pragma unroll 8
  for (int kk = 0; kk < 64; kk++) {
    float wv = ldT<DT>(W1, wb1 + kk * 256 + tid);
#pragma unroll
    for (int r = 0; r < 8; r++) acc1[r] += bcastlane(hreg[r], kk) * wv;
  }
#pragma unroll
  for (int r = 0; r < 8; r++) sf[r][tid] = fmaxf(acc1[r], 0.f);
  __syncthreads();
  int k0 = wid * 64;
  float sreg[8];
#pragma unroll
  for (int r = 0; r < 8; r++) sreg[r] = sf[r][k0 + lane];
  long wb2 = (long)(l * 3 + d) * 16384;
  float a2[8];
#pragma unroll
  for (int r = 0; r < 8; r++) a2[r] = 0.f;
#pragma unroll 8
  for (int kk = 0; kk < 64; kk++) {
    float w2 = ldT<DT>(W2, wb2 + (long)(k0 + kk) * 64 + lane);
#pragma unroll
    for (int r = 0; r < 8; r++) a2[r] += bcastlane(sreg[r], kk) * w2;
  }
#pragma unroll
  for (int r = 0; r < 8; r++) sp[wid][r][lane] = a2[r];
  __syncthreads();
  for (int rr = 0; rr < 2; rr++) {
    int r = wid * 2 + rr;
    int row = row0 + r;
    float x = sh[r][lane] + ldT<DT>(b2, gb + lane) +
              sp[0][r][lane] + sp[1][r][lane] + sp[2][r][lane] + sp[3][r][lane];
    float mu = wred64(x) * 0.015625f;
    float dx = x - mu;
    float var = wred64(dx * dx) * 0.015625f;
    hout[(long)row * 64 + lane] =
        dx * rsqrtf(var + 1e-5f) * ldT<DT>(g2, gb + lane) + ldT<DT>(be2, gb + lane);
  }
}
__global__ void ct67_ffn(const float* h, const float* obuf, float* hout,
                         const void* W1, const void* b1, const void* W2, const void* b2,
                         const void* g1, const void* be1, const void* g2, const void* be2,
                         int l, const int* dtp) {
  int dt = dtp[0];
  if (dt == 0)      ffn_body<0>(h, obuf, hout, W1, b1, W2, b2, g1, be1, g2, be2, l);
  else if (dt == 1) ffn_body<1>(h, obuf, hout, W1, b1, W2, b2, g1, be1, g2, be2, l);
  else              ffn_body<2>(h, obuf, hout, W1, b1, W2, b2, g1, be1, g2, be2, l);
}

// ---------------- pooling stage 1: 256 blocks of partials ----------------
__global__ void ct67_poolp(const float* h, const int* ranges, float* ppart) {
  int b = blockIdx.x;
  int c = blockIdx.y;
  int j = threadIdx.x;
  float s = 0.f;
  for (int d = 0; d < 3; d++) {
    int st = ranges[(d * 8 + b) * 2], en = ranges[(d * 8 + b) * 2 + 1];
    int ro = (d == 0) ? 0 : ((d == 1) ? 1536 : 4608);
    for (int r = st + c; r < en; r += 32) s += h[(long)(ro + r) * 64 + j];
  }
  ppart[(long)(b * 32 + c) * 64 + j] = s;
}

// ---------------- merged pool-final + head MLP (1 block, 512 threads) ----------------
template <int DT>
__device__ void poolmlp_body(const float* ppart, const int* ranges,
                             const void* Wh1, const void* bh1, const void* Wh2,
                             const void* bh2, const void* Wh3, const void* bh3,
                             float* out) {
  __shared__ float pooled[8][64];
  __shared__ float y1[8][64];
  __shared__ float y2[8][64];
  int tid = threadIdx.x;
  int b = tid / 64, j = tid % 64;
  float s = 0.f;
  for (int c = 0; c < 32; c++) s += ppart[(long)(b * 32 + c) * 64 + j];
  int cnt = 0;
  for (int d = 0; d < 3; d++)
    cnt += ranges[(d * 8 + b) * 2 + 1] - ranges[(d * 8 + b) * 2];
  pooled[b][j] = (cnt > 0) ? (s / (float)cnt) : 0.f;
  __syncthreads();
  float acc = ldT<DT>(bh1, j);
  for (int kk = 0; kk < 64; kk++) acc += pooled[b][kk] * ldT<DT>(Wh1, kk * 64 + j);
  y1[b][j] = fmaxf(acc, 0.f);
  __syncthreads();
  acc = ldT<DT>(bh2, j);
  for (int kk = 0; kk < 64; kk++) acc += y1[b][kk] * ldT<DT>(Wh2, kk * 64 + j);
  y2[b][j] = fmaxf(acc, 0.f);
  __syncthreads();
  if (j < 10) {
    float o = ldT<DT>(bh3, j);
    for (int kk = 0; kk < 64; kk++) o += y2[b][kk] * ldT<DT>(Wh3, kk * 10 + j);
    out[b * 10 + j] = o;
  }
}
__global__ void ct67_poolmlp(const float* ppart, const int* ranges,
                             const void* Wh1, const void* bh1, const void* Wh2,
                             const void* bh2, const void* Wh3, const void* bh3,
                             float* out, const int* dtp) {
  int dt = dtp[0];
  if (dt == 0)      poolmlp_body<0>(ppart, ranges, Wh1, bh1, Wh2, bh2, Wh3, bh3, out);
  else if (dt == 1) poolmlp_body<1>(ppart, ranges, Wh1, bh1, Wh2, bh2, Wh3, bh3, out);
  else              poolmlp_body<2>(ppart, ranges, Wh1, bh1, Wh2, bh2, Wh3, bh3, out);
}

extern "C" void kernel_launch(void* const* d_in, const int* in_sizes, int n_in,
                              void* d_out, int out_size, void* d_ws, size_t ws_size,
                              hipStream_t stream) {
  (void)in_sizes; (void)n_in; (void)out_size;
  const void* x0 = d_in[0];  const void* pe0 = d_in[1];  const int* bel0 = (const int*)d_in[2];
  const void* x1 = d_in[3];  const void* pe1 = d_in[4];  const int* bel1 = (const int*)d_in[5];
  const void* x2 = d_in[6];  const void* pe2 = d_in[7];  const int* bel2 = (const int*)d_in[8];
  const void* adj00 = d_in[9];  const void* adj11 = d_in[10]; const void* adj22 = d_in[11];
  const void* b01 = d_in[12];   const void* b12 = d_in[13];
  const void* Wf0 = d_in[14]; const void* bf0 = d_in[15]; const void* Wp0 = d_in[16];
  const void* Wf1 = d_in[17]; const void* bf1 = d_in[18]; const void* Wp1 = d_in[19];
  const void* Wf2 = d_in[20]; const void* bf2 = d_in[21]; const void* Wp2 = d_in[22];
  const void* Wq = d_in[23]; const void* bq = d_in[24];
  const void* Wk = d_in[25]; const void* bk = d_in[26];
  const void* Wv = d_in[27]; const void* bv = d_in[28];
  const void* Wo = d_in[29]; const void* bo = d_in[30];
  const void* g1 = d_in[31]; const void* be1 = d_in[32];
  const void* g2 = d_in[33]; const void* be2 = d_in[34];
  const void* Wff1 = d_in[35]; const void* bff1 = d_in[36];
  const void* Wff2 = d_in[37]; const void* bff2 = d_in[38];
  const void* Wh1 = d_in[39]; const void* bh1 = d_in[40];
  const void* Wh2 = d_in[41]; const void* bh2 = d_in[42];
  const void* Wh3 = d_in[43]; const void* bh3 = d_in[44];

  char* w = (char*)d_ws;
  float* hbuf   = (float*)(w + 0);          // 1572864
  float* obuf   = (float*)(w + 1572864);    // -> 5505024
  float* qb     = (float*)(w + 5505024);    // -> 9437184
  float* kb     = (float*)(w + 9437184);    // -> 13369344
  float* vb     = (float*)(w + 13369344);   // -> 17301504
  int* ranges   = (int*)(w + 17301504);     // -> 17301696
  int* flags    = (int*)(w + 17301696);     // -> 17301760
  float* ppart  = (float*)(w + 17301760);   // -> 17367296
  int* ell      = (int*)(w + 17367296);     // -> 25231616
  int* nnz      = (int*)(w + 25231616);     // -> 25293056
  int ellok = (ws_size >= (size_t)25293056) ? 1 : 0;

  ct67_init<<<1, 64, 0, stream>>>((const unsigned short*)x0, bel0, bel1, bel2, ranges, flags);
  ct67_ellem<<<4242, 256, 0, stream>>>(adj00, b01, adj11, b12, adj22,
                                       bel0, bel1, bel2, ranges, ell, nnz,
                                       x0, pe0, Wf0, bf0, Wp0, x1, pe1, Wf1, bf1, Wp1,
                                       x2, pe2, Wf2, bf2, Wp2, hbuf, flags);
  for (int l = 0; l < 2; l++) {
    ct67_qkv<<<720, 512, 0, stream>>>(hbuf, Wq, bq, Wk, bk, Wv, bv, qb, kb, vb, l, flags);
    CellularTransformer_67345087201410_kernel<<<1920, 512, 0, stream>>>(
        qb, kb, vb, Wo, bo, adj00, b01, adj11, b12, adj22,
        bel0, bel1, bel2, ranges, ell, nnz, ellok, obuf, l, flags);
    ct67_ffn<<<768, 256, 0, stream>>>(hbuf, obuf, hbuf, Wff1, bff1, Wff2, bff2,
                                      g1, be1, g2, be2, l, flags);
  }
  ct67_poolp<<<dim3(8, 32), 64, 0, stream>>>(hbuf, ranges, ppart);
  ct67_poolmlp<<<1, 512, 0, stream>>>(ppart, ranges, Wh1, bh1, Wh2, bh2, Wh3, bh3,
                                      (float*)d_out, flags);
}

// Round 4
// 355.388 us; speedup vs baseline: 2.5158x; 1.6045x over previous
//
#include <hip/hip_runtime.h>
#include <hip/hip_bf16.h>
#include <hip/hip_fp16.h>

// Storage-dtype-templated load: DT=0 bf16, DT=1 fp16, DT=2 f32.
template <int DT>
__device__ __forceinline__ float ldT(const void* p, long i) {
  if (DT == 0) {
    unsigned int a = ((unsigned int)((const unsigned short*)p)[i]) << 16;
    union { unsigned int u; float f; } c; c.u = a; return c.f;
  } else if (DT == 1) {
    return __half2float(((const __half*)p)[i]);
  } else {
    return ((const float*)p)[i];
  }
}
template <int DT>
__device__ __forceinline__ bool msknzT(const void* p, long i) {
  if (DT < 2) return ((const unsigned short*)p)[i] != 0;  // 0.0 encodes as 0x0000
  return ((const float*)p)[i] != 0.f;
}
__device__ __forceinline__ float wred64(float v) {
#pragma unroll
  for (int off = 1; off < 64; off <<= 1) v += __shfl_xor(v, off, 64);
  return v;
}
// wave-uniform broadcast of lane l's value (v_readlane -> SGPR operand)
__device__ __forceinline__ float bcastlane(float v, int l) {
  return __int_as_float(__builtin_amdgcn_readlane(__float_as_int(v), l));
}
__device__ __forceinline__ void ct67_itab(int bi, int& i, int& t) {
  const int toff[8] = {0, 1536, 4608, 6144, 9216, 10752, 13824, 15360};
  i = 0;
  while (bi >= toff[i + 1]) i++;
  t = bi - toff[i];
}
template <int DT>
__device__ __forceinline__ void ct67_mask(int i, const void* adj00, const void* b01,
                                          const void* adj11, const void* b12,
                                          const void* adj22, const void*& mp,
                                          long& mts, long& mss) {
  switch (i) {
    case 0: mp = adj00; mts = 1536; mss = 1; break;
    case 1: mp = b01;   mts = 1;    mss = 3072; break;
    case 2: mp = b01;   mts = 3072; mss = 1; break;
    case 3: mp = adj11; mts = 3072; mss = 1; break;
    case 4: mp = b12;   mts = 1;    mss = 1536; break;
    case 5: mp = b12;   mts = 1536; mss = 1; break;
    default: mp = adj22; mts = 1536; mss = 1; break;
  }
}

// ---------------- init: dtype classify + batch ranges ----------------
__global__ void ct67_init(const unsigned short* x0u, const int* b0, const int* b1,
                          const int* b2, int* ranges, int* flags) {
  int t = threadIdx.x;
  if (t == 63) {
    float vals[32], mean = 0.f, var = 0.f;
    for (int i = 0; i < 32; i++) {
      union { unsigned int u; float f; } c;
      c.u = ((unsigned int)x0u[i]) << 16;
      vals[i] = c.f; mean += c.f;
    }
    mean /= 32.f;
    for (int i = 0; i < 32; i++) var += (vals[i] - mean) * (vals[i] - mean);
    var /= 32.f;
    flags[0] = (var < 1e-6f) ? 1 : ((var < 1e3f) ? 0 : 2);
  }
  if (t < 24) {
    int d = t / 8, b = t % 8;
    const int* bel = (d == 0) ? b0 : ((d == 1) ? b1 : b2);
    int N = (d == 1) ? 3072 : 1536;
    int lo = 0, hi = N;
    while (lo < hi) { int m = (lo + hi) / 2; if (bel[m] < b) lo = m + 1; else hi = m; }
    int st = lo; hi = N;
    while (lo < hi) { int m = (lo + hi) / 2; if (bel[m] < b + 1) lo = m + 1; else hi = m; }
    ranges[t * 2] = st;
    ranges[t * 2 + 1] = lo;
  }
}

// ---------------- merged ELL-build + embed (independent stages, one launch) ------
// blocks [0,3840): ELL build, 4 waves x 1 row each (ballot scan; high TLP hides
//   the strided loads of the transposed interactions — round-3's low-parallelism
//   coalesced variant was 6x slower, reverted).
// blocks [3840,5376): embed 4 rows.
template <int DT>
__device__ void ellem_body(const void* adj00, const void* b01, const void* adj11,
                           const void* b12, const void* adj22,
                           const int* bel0, const int* bel1, const int* bel2,
                           const int* ranges, int* ell, int* nnz,
                           const void* x0, const void* pe0, const void* wf0,
                           const void* bf0, const void* wp0, const void* x1,
                           const void* pe1, const void* wf1, const void* bf1,
                           const void* wp1, const void* x2, const void* pe2,
                           const void* wf2, const void* bf2, const void* wp2,
                           float* hout) {
  int tid = threadIdx.x;
  int lane = tid % 64, wid = tid / 64;
  if (blockIdx.x < 3840) {
    const int sdv[7] = {0, 0, 1, 1, 1, 2, 2};
    const int tdv[7] = {0, 1, 0, 1, 2, 1, 2};
    int bi = blockIdx.x * 4 + wid;
    int i, t;
    ct67_itab(bi, i, t);
    const void* mp; long mts, mss;
    ct67_mask<DT>(i, adj00, b01, adj11, b12, adj22, mp, mts, mss);
    const int* belt = (tdv[i] == 0) ? bel0 : ((tdv[i] == 1) ? bel1 : bel2);
    int b = belt[t];
    if (b < 0) b = 0;
    if (b > 7) b = 7;
    const int* rng = ranges + sdv[i] * 16;
    int s0 = rng[b * 2], s1 = rng[b * 2 + 1];
    int base = 0;
    for (int s = s0; s < s1; s += 64) {
      int ss = s + lane;
      bool pred = false;
      if (ss < s1) pred = msknzT<DT>(mp, (long)t * mts + (long)ss * mss);
      unsigned long long bal = __ballot(pred);
      int pos = __popcll(bal & ((1ull << lane) - 1ull));
      if (pred && base + pos < 128) ell[(long)bi * 128 + base + pos] = ss;
      base += __popcll(bal);
    }
    if (lane == 0) nnz[bi] = base;
  } else {
    int row = (blockIdx.x - 3840) * 4 + wid;
    int d = (row < 1536) ? 0 : ((row < 4608) ? 1 : 2);
    int r = row - ((d == 0) ? 0 : ((d == 1) ? 1536 : 4608));
    const void* x  = (d == 0) ? x0  : ((d == 1) ? x1  : x2);
    const void* pe = (d == 0) ? pe0 : ((d == 1) ? pe1 : pe2);
    const void* wf = (d == 0) ? wf0 : ((d == 1) ? wf1 : wf2);
    const void* bf = (d == 0) ? bf0 : ((d == 1) ? bf1 : bf2);
    const void* wp = (d == 0) ? wp0 : ((d == 1) ? wp1 : wp2);
    float acc = ldT<DT>(bf, lane);
#pragma unroll 8
    for (int f = 0; f < 32; f++)
      acc += ldT<DT>(x, (long)r * 32 + f) * ldT<DT>(wf, f * 64 + lane);
#pragma unroll 8
    for (int q = 0; q < 16; q++)
      acc += ldT<DT>(pe, (long)r * 16 + q) * ldT<DT>(wp, q * 64 + lane);
    hout[(long)row * 64 + lane] = acc;
  }
}
__global__ void ct67_ellem(const void* adj00, const void* b01, const void* adj11,
                           const void* b12, const void* adj22,
                           const int* bel0, const int* bel1, const int* bel2,
                           const int* ranges, int* ell, int* nnz,
                           const void* x0, const void* pe0, const void* wf0,
                           const void* bf0, const void* wp0, const void* x1,
                           const void* pe1, const void* wf1, const void* bf1,
                           const void* wp1, const void* x2, const void* pe2,
                           const void* wf2, const void* bf2, const void* wp2,
                           float* hout, const int* dtp) {
  int dt = dtp[0];
  if (dt == 0)
    ellem_body<0>(adj00,b01,adj11,b12,adj22,bel0,bel1,bel2,ranges,ell,nnz,
                  x0,pe0,wf0,bf0,wp0,x1,pe1,wf1,bf1,wp1,x2,pe2,wf2,bf2,wp2,hout);
  else if (dt == 1)
    ellem_body<1>(adj00,b01,adj11,b12,adj22,bel0,bel1,bel2,ranges,ell,nnz,
                  x0,pe0,wf0,bf0,wp0,x1,pe1,wf1,bf1,wp1,x2,pe2,wf2,bf2,wp2,hout);
  else
    ellem_body<2>(adj00,b01,adj11,b12,adj22,bel0,bel1,bel2,ranges,ell,nnz,
                  x0,pe0,wf0,bf0,wp0,x1,pe1,wf1,bf1,wp1,x2,pe2,wf2,bf2,wp2,hout);
}

// ---------------- qkv: 64 rows/block (8 waves x 8 rows, readlane broadcast) ------
template <int DT>
__device__ void qkv_body(const float* h, const void* Wq, const void* bq, const void* Wk,
                         const void* bk, const void* Wv, const void* bv,
                         float* qd, float* kd, float* vd, int l) {
  const int segend[21] = {1536, 3072, 4608, 7680, 9216, 10752, 12288, 15360, 18432,
                          21504, 24576, 27648, 29184, 32256, 35328, 38400, 39936,
                          41472, 43008, 44544, 46080};
  const int segsrc[21] = {0, 0, 0, 1, 0, 0, 0, 1, 1, 1, 1, 1, 2, 1, 1, 1, 2, 2, 2, 2, 2};
  const int segdst[21] = {0, 0, 0, 1536, 1536, 1536, 4608, 3072, 3072, 6144, 6144, 6144,
                          9216, 9216, 9216, 10752, 12288, 12288, 13824, 13824, 13824};
  const int rowoff[3] = {0, 1536, 4608};
  __shared__ float sW[4096];
  int tid = threadIdx.x;
  int lane = tid & 63;
  int wid = tid >> 6;
  int gbase = blockIdx.x * 64;
  int seg = 0;
  while (gbase >= segend[seg]) seg++;
  int segstart = (seg == 0) ? 0 : segend[seg - 1];
  int i = seg / 3, role = seg - i * 3;
  const void* W = (role == 0) ? Wq : (role == 1) ? Wk : Wv;
  const void* bbp = (role == 0) ? bq : (role == 1) ? bk : bv;
  long wbase = (long)(l * 7 + i) * 4096;
#pragma unroll
  for (int kkk = 0; kkk < 8; kkk++) {
    int idx = tid + kkk * 512;
    sW[idx] = ldT<DT>(W, wbase + idx);
  }
  int rbase = gbase - segstart + wid * 8;
  int hrow0 = rowoff[segsrc[seg]] + rbase;
  float hreg[8];
#pragma unroll
  for (int rr = 0; rr < 8; rr++) hreg[rr] = h[(long)(hrow0 + rr) * 64 + lane];
  __syncthreads();
  float bias = ldT<DT>(bbp, (long)(l * 7 + i) * 64 + lane);
  float acc[8];
#pragma unroll
  for (int rr = 0; rr < 8; rr++) acc[rr] = bias;
#pragma unroll 8
  for (int kk = 0; kk < 64; kk++) {
    float wv = sW[kk * 64 + lane];
#pragma unroll
    for (int rr = 0; rr < 8; rr++)
      acc[rr] += bcastlane(hreg[rr], kk) * wv;
  }
  float* dst = (role == 0) ? qd : (role == 1) ? kd : vd;
#pragma unroll
  for (int rr = 0; rr < 8; rr++)
    dst[(long)(segdst[seg] + rbase + rr) * 64 + lane] = acc[rr];
}
__global__ void ct67_qkv(const float* h, const void* Wq, const void* bq, const void* Wk,
                         const void* bk, const void* Wv, const void* bv,
                         float* qd, float* kd, float* vd, int l, const int* dtp) {
  int dt = dtp[0];
  if (dt == 0)      qkv_body<0>(h, Wq, bq, Wk, bk, Wv, bv, qd, kd, vd, l);
  else if (dt == 1) qkv_body<1>(h, Wq, bq, Wk, bk, Wv, bv, qd, kd, vd, l);
  else              qkv_body<2>(h, Wq, bq, Wk, bk, Wv, bv, qd, kd, vd, l);
}

// ---------------- attention + output projection: 8 rows/block, Wo staged in LDS --
template <int DT>
__device__ void attn_body(const float* qb, const float* kb, const float* vb,
                          const void* Wo, const void* bo,
                          const void* adj00, const void* b01, const void* adj11,
                          const void* b12, const void* adj22,
                          const int* bel0, const int* bel1, const int* bel2,
                          const int* ranges, const int* ell, const int* nnz, int ellok,
                          float* obuf, int l) {
  const int koff[7] = {0, 1536, 3072, 6144, 9216, 12288, 13824};
  const int sdv[7] = {0, 0, 1, 1, 1, 2, 2};
  const int tdv[7] = {0, 1, 0, 1, 2, 1, 2};
  __shared__ float sWo[4096];
  int tid = threadIdx.x;
  int lane = tid & 63;
  int wid = tid >> 6;
  int bi = blockIdx.x * 8 + wid;
  // all 8 rows of a block share one interaction i (i-boundaries are multiples of 8)
  int i0, t0;
  ct67_itab(blockIdx.x * 8, i0, t0);
  long wobase = (long)(l * 7 + i0) * 4096;
  for (int idx = tid; idx < 4096; idx += 512) sWo[idx] = ldT<DT>(Wo, wobase + idx);
  int i, t;
  ct67_itab(bi, i, t);
  int hh = lane / 8, jj = lane % 8;
  const float4* qp = (const float4*)(qb + (long)bi * 64 + hh * 8);
  float4 q0 = qp[0], q1 = qp[1];
  const float* kbase = kb + (long)koff[i] * 64 + hh * 8;
  const float* vbase = vb + (long)koff[i] * 64 + hh * 8;
  float mr = -1e30f, lr = 0.f, o[8];
#pragma unroll
  for (int d = 0; d < 8; d++) o[d] = 0.f;
  int n = ellok ? nnz[bi] : 129;
  if (n <= 128) {
    const int* hl = ell + (long)bi * 128;
    for (int hidx = jj; hidx < n; hidx += 8) {
      int s = hl[hidx];
      const float4* kp = (const float4*)(kbase + (long)s * 64);
      float4 k0 = kp[0], k1 = kp[1];
      float sc = q0.x * k0.x + q0.y * k0.y + q0.z * k0.z + q0.w * k0.w +
                 q1.x * k1.x + q1.y * k1.y + q1.z * k1.z + q1.w * k1.w;
      sc *= 0.35355339059327373f;
      float nm = fmaxf(mr, sc);
      float fo = expf(mr - nm);
      float wv = expf(sc - nm);
      lr = lr * fo + wv;
      const float4* vp = (const float4*)(vbase + (long)s * 64);
      float4 v0 = vp[0], v1 = vp[1];
      o[0] = o[0] * fo + wv * v0.x; o[1] = o[1] * fo + wv * v0.y;
      o[2] = o[2] * fo + wv * v0.z; o[3] = o[3] * fo + wv * v0.w;
      o[4] = o[4] * fo + wv * v1.x; o[5] = o[5] * fo + wv * v1.y;
      o[6] = o[6] * fo + wv * v1.z; o[7] = o[7] * fo + wv * v1.w;
      mr = nm;
    }
  } else {  // fallback: in-loop mask scan (overflow rows or no ELL workspace)
    const void* mp; long mts, mss;
    ct67_mask<DT>(i, adj00, b01, adj11, b12, adj22, mp, mts, mss);
    const int* belt = (tdv[i] == 0) ? bel0 : ((tdv[i] == 1) ? bel1 : bel2);
    int b = belt[t];
    if (b < 0) b = 0;
    if (b > 7) b = 7;
    const int* rng = ranges + sdv[i] * 16;
    int s0 = rng[b * 2], s1 = rng[b * 2 + 1];
    for (int s = s0 + jj; s < s1; s += 8) {
      if (msknzT<DT>(mp, (long)t * mts + (long)s * mss)) {
        const float4* kp = (const float4*)(kbase + (long)s * 64);
        float4 k0 = kp[0], k1 = kp[1];
        float sc = q0.x * k0.x + q0.y * k0.y + q0.z * k0.z + q0.w * k0.w +
                   q1.x * k1.x + q1.y * k1.y + q1.z * k1.z + q1.w * k1.w;
        sc *= 0.35355339059327373f;
        float nm = fmaxf(mr, sc);
        float fo = expf(mr - nm);
        float wv = expf(sc - nm);
        lr = lr * fo + wv;
        const float4* vp = (const float4*)(vbase + (long)s * 64);
        float4 v0 = vp[0], v1 = vp[1];
        o[0] = o[0] * fo + wv * v0.x; o[1] = o[1] * fo + wv * v0.y;
        o[2] = o[2] * fo + wv * v0.z; o[3] = o[3] * fo + wv * v0.w;
        o[4] = o[4] * fo + wv * v1.x; o[5] = o[5] * fo + wv * v1.y;
        o[6] = o[6] * fo + wv * v1.z; o[7] = o[7] * fo + wv * v1.w;
        mr = nm;
      }
    }
  }
  // merge 8 lanes per head via xor-butterfly (verified r13)
#pragma unroll
  for (int off = 1; off < 8; off <<= 1) {
    float m2 = __shfl_xor(mr, off, 64);
    float l2 = __shfl_xor(lr, off, 64);
    float nm = fmaxf(mr, m2);
    float f1 = expf(mr - nm), f2 = expf(m2 - nm);
    lr = lr * f1 + l2 * f2;
#pragma unroll
    for (int d = 0; d < 8; d++) {
      float o2 = __shfl_xor(o[d], off, 64);
      o[d] = o[d] * f1 + o2 * f2;
    }
    mr = nm;
  }
  float val[8];
#pragma unroll
  for (int d = 0; d < 8; d++) val[d] = (lr > 0.f) ? (o[d] / lr) : 0.f;
  __syncthreads();
  // Wo projection from LDS: readlane broadcast + FMA (same e/g order as before)
  float acc = ldT<DT>(bo, (long)(l * 7 + i) * 64 + lane);
  for (int g = 0; g < 8; g++) {
#pragma unroll
    for (int e = 0; e < 8; e++) {
      float sv = bcastlane(val[e], g * 8);
      acc += sv * sWo[(g * 8 + e) * 64 + lane];
    }
  }
  obuf[(long)bi * 64 + lane] = acc;
}
__global__ void CellularTransformer_67345087201410_kernel(
    const float* qb, const float* kb, const float* vb, const void* Wo, const void* bo,
    const void* adj00, const void* b01, const void* adj11, const void* b12,
    const void* adj22, const int* bel0, const int* bel1, const int* bel2,
    const int* ranges, const int* ell, const int* nnz, int ellok,
    float* obuf, int l, const int* dtp) {
  int dt = dtp[0];
  if (dt == 0)
    attn_body<0>(qb,kb,vb,Wo,bo,adj00,b01,adj11,b12,adj22,bel0,bel1,bel2,ranges,ell,nnz,ellok,obuf,l);
  else if (dt == 1)
    attn_body<1>(qb,kb,vb,Wo,bo,adj00,b01,adj11,b12,adj22,bel0,bel1,bel2,ranges,ell,nnz,ellok,obuf,l);
  else
    attn_body<2>(qb,kb,vb,Wo,bo,adj00,b01,adj11,b12,adj22,bel0,bel1,bel2,ranges,ell,nnz,ellok,obuf,l);
}

// ---------------- fused FFN: 8 rows/block, register-tiled FF1/FF2 ----------------
template <int DT>
__device__ void ffn_body(const float* h, const float* obuf, float* hout,
                         const void* W1, const void* b1, const void* W2, const void* b2,
                         const void* g1, const void* be1, const void* g2, const void* be2,
                         int l) {
  __shared__ float sh[8][64];
  __shared__ float sf[8][256];
  __shared__ float sp[4][8][64];
  int tid = threadIdx.x;
  int lane = tid & 63;
  int wid = tid >> 6;
  int row0 = blockIdx.x * 8;
  int d = (row0 < 1536) ? 0 : ((row0 < 4608) ? 1 : 2);
  long gb = (long)(l * 3 + d) * 64;
  for (int rr = 0; rr < 2; rr++) {
    int r = wid * 2 + rr;
    int row = row0 + r;
    float x = h[(long)row * 64 + lane];
    if (d == 0) {
      int rw = row;
      x += obuf[(long)rw * 64 + lane] + obuf[(long)(4608 + rw) * 64 + lane];
    } else if (d == 1) {
      int rw = row - 1536;
      x += obuf[(long)(1536 + rw) * 64 + lane] + obuf[(long)(6144 + rw) * 64 + lane] +
           obuf[(long)(10752 + rw) * 64 + lane];
    } else {
      int rw = row - 4608;
      x += obuf[(long)(9216 + rw) * 64 + lane] + obuf[(long)(13824 + rw) * 64 + lane];
    }
    float mu = wred64(x) * 0.015625f;
    float dx = x - mu;
    float var = wred64(dx * dx) * 0.015625f;
    sh[r][lane] = dx * rsqrtf(var + 1e-5f) * ldT<DT>(g1, gb + lane) + ldT<DT>(be1, gb + lane);
  }
  __syncthreads();
  float hreg[8];
#pragma unroll
  for (int r = 0; r < 8; r++) hreg[r] = sh[r][lane];
  long wb1 = (long)(l * 3 + d) * 16384;
  float bb1 = ldT<DT>(b1, (long)(l * 3 + d) * 256 + tid);
  float acc1[8];
#pragma unroll
  for (int r = 0; r < 8; r++) acc1[r] = bb1;
#pragma unroll 8
  for (int kk = 0; kk < 64; kk++) {
    float wv = ldT<DT>(W1, wb1 + kk * 256 + tid);
#pragma unroll
    for (int r = 0; r < 8; r++) acc1[r] += bcastlane(hreg[r], kk) * wv;
  }
#pragma unroll
  for (int r = 0; r < 8; r++) sf[r][tid] = fmaxf(acc1[r], 0.f);
  __syncthreads();
  int k0 = wid * 64;
  float sreg[8];
#pragma unroll
  for (int r = 0; r < 8; r++) sreg[r] = sf[r][k0 + lane];
  long wb2 = (long)(l * 3 + d) * 16384;
  float a2[8];
#pragma unroll
  for (int r = 0; r < 8; r++) a2[r] = 0.f;
#pragma unroll 8
  for (int kk = 0; kk < 64; kk++) {
    float w2 = ldT<DT>(W2, wb2 + (long)(k0 + kk) * 64 + lane);
#pragma unroll
    for (int r = 0; r < 8; r++) a2[r] += bcastlane(sreg[r], kk) * w2;
  }
#pragma unroll
  for (int r = 0; r < 8; r++) sp[wid][r][lane] = a2[r];
  __syncthreads();
  for (int rr = 0; rr < 2; rr++) {
    int r = wid * 2 + rr;
    int row = row0 + r;
    float x = sh[r][lane] + ldT<DT>(b2, gb + lane) +
              sp[0][r][lane] + sp[1][r][lane] + sp[2][r][lane] + sp[3][r][lane];
    float mu = wred64(x) * 0.015625f;
    float dx = x - mu;
    float var = wred64(dx * dx) * 0.015625f;
    hout[(long)row * 64 + lane] =
        dx * rsqrtf(var + 1e-5f) * ldT<DT>(g2, gb + lane) + ldT<DT>(be2, gb + lane);
  }
}
__global__ void ct67_ffn(const float* h, const float* obuf, float* hout,
                         const void* W1, const void* b1, const void* W2, const void* b2,
                         const void* g1, const void* be1, const void* g2, const void* be2,
                         int l, const int* dtp) {
  int dt = dtp[0];
  if (dt == 0)      ffn_body<0>(h, obuf, hout, W1, b1, W2, b2, g1, be1, g2, be2, l);
  else if (dt == 1) ffn_body<1>(h, obuf, hout, W1, b1, W2, b2, g1, be1, g2, be2, l);
  else              ffn_body<2>(h, obuf, hout, W1, b1, W2, b2, g1, be1, g2, be2, l);
}

// ---------------- pooling stage 1: 256 blocks of partials ----------------
__global__ void ct67_poolp(const float* h, const int* ranges, float* ppart) {
  int b = blockIdx.x;
  int c = blockIdx.y;
  int j = threadIdx.x;
  float s = 0.f;
  for (int d = 0; d < 3; d++) {
    int st = ranges[(d * 8 + b) * 2], en = ranges[(d * 8 + b) * 2 + 1];
    int ro = (d == 0) ? 0 : ((d == 1) ? 1536 : 4608);
    for (int r = st + c; r < en; r += 32) s += h[(long)(ro + r) * 64 + j];
  }
  ppart[(long)(b * 32 + c) * 64 + j] = s;
}

// ---------------- merged pool-final + head MLP (1 block, 512 threads) ----------------
template <int DT>
__device__ void poolmlp_body(const float* ppart, const int* ranges,
                             const void* Wh1, const void* bh1, const void* Wh2,
                             const void* bh2, const void* Wh3, const void* bh3,
                             float* out) {
  __shared__ float pooled[8][64];
  __shared__ float y1[8][64];
  __shared__ float y2[8][64];
  int tid = threadIdx.x;
  int b = tid / 64, j = tid % 64;
  float s = 0.f;
  for (int c = 0; c < 32; c++) s += ppart[(long)(b * 32 + c) * 64 + j];
  int cnt = 0;
  for (int d = 0; d < 3; d++)
    cnt += ranges[(d * 8 + b) * 2 + 1] - ranges[(d * 8 + b) * 2];
  pooled[b][j] = (cnt > 0) ? (s / (float)cnt) : 0.f;
  __syncthreads();
  float acc = ldT<DT>(bh1, j);
  for (int kk = 0; kk < 64; kk++) acc += pooled[b][kk] * ldT<DT>(Wh1, kk * 64 + j);
  y1[b][j] = fmaxf(acc, 0.f);
  __syncthreads();
  acc = ldT<DT>(bh2, j);
  for (int kk = 0; kk < 64; kk++) acc += y1[b][kk] * ldT<DT>(Wh2, kk * 64 + j);
  y2[b][j] = fmaxf(acc, 0.f);
  __syncthreads();
  if (j < 10) {
    float o = ldT<DT>(bh3, j);
    for (int kk = 0; kk < 64; kk++) o += y2[b][kk] * ldT<DT>(Wh3, kk * 10 + j);
    out[b * 10 + j] = o;
  }
}
__global__ void ct67_poolmlp(const float* ppart, const int* ranges,
                             const void* Wh1, const void* bh1, const void* Wh2,
                             const void* bh2, const void* Wh3, const void* bh3,
                             float* out, const int* dtp) {
  int dt = dtp[0];
  if (dt == 0)      poolmlp_body<0>(ppart, ranges, Wh1, bh1, Wh2, bh2, Wh3, bh3, out);
  else if (dt == 1) poolmlp_body<1>(ppart, ranges, Wh1, bh1, Wh2, bh2, Wh3, bh3, out);
  else              poolmlp_body<2>(ppart, ranges, Wh1, bh1, Wh2, bh2, Wh3, bh3, out);
}

extern "C" void kernel_launch(void* const* d_in, const int* in_sizes, int n_in,
                              void* d_out, int out_size, void* d_ws, size_t ws_size,
                              hipStream_t stream) {
  (void)in_sizes; (void)n_in; (void)out_size;
  const void* x0 = d_in[0];  const void* pe0 = d_in[1];  const int* bel0 = (const int*)d_in[2];
  const void* x1 = d_in[3];  const void* pe1 = d_in[4];  const int* bel1 = (const int*)d_in[5];
  const void* x2 = d_in[6];  const void* pe2 = d_in[7];  const int* bel2 = (const int*)d_in[8];
  const void* adj00 = d_in[9];  const void* adj11 = d_in[10]; const void* adj22 = d_in[11];
  const void* b01 = d_in[12];   const void* b12 = d_in[13];
  const void* Wf0 = d_in[14]; const void* bf0 = d_in[15]; const void* Wp0 = d_in[16];
  const void* Wf1 = d_in[17]; const void* bf1 = d_in[18]; const void* Wp1 = d_in[19];
  const void* Wf2 = d_in[20]; const void* bf2 = d_in[21]; const void* Wp2 = d_in[22];
  const void* Wq = d_in[23]; const void* bq = d_in[24];
  const void* Wk = d_in[25]; const void* bk = d_in[26];
  const void* Wv = d_in[27]; const void* bv = d_in[28];
  const void* Wo = d_in[29]; const void* bo = d_in[30];
  const void* g1 = d_in[31]; const void* be1 = d_in[32];
  const void* g2 = d_in[33]; const void* be2 = d_in[34];
  const void* Wff1 = d_in[35]; const void* bff1 = d_in[36];
  const void* Wff2 = d_in[37]; const void* bff2 = d_in[38];
  const void* Wh1 = d_in[39]; const void* bh1 = d_in[40];
  const void* Wh2 = d_in[41]; const void* bh2 = d_in[42];
  const void* Wh3 = d_in[43]; const void* bh3 = d_in[44];

  char* w = (char*)d_ws;
  float* hbuf   = (float*)(w + 0);          // 1572864
  float* obuf   = (float*)(w + 1572864);    // -> 5505024
  float* qb     = (float*)(w + 5505024);    // -> 9437184
  float* kb     = (float*)(w + 9437184);    // -> 13369344
  float* vb     = (float*)(w + 13369344);   // -> 17301504
  int* ranges   = (int*)(w + 17301504);     // -> 17301696
  int* flags    = (int*)(w + 17301696);     // -> 17301760
  float* ppart  = (float*)(w + 17301760);   // -> 17367296
  int* ell      = (int*)(w + 17367296);     // -> 25231616
  int* nnz      = (int*)(w + 25231616);     // -> 25293056
  int ellok = (ws_size >= (size_t)25293056) ? 1 : 0;

  ct67_init<<<1, 64, 0, stream>>>((const unsigned short*)x0, bel0, bel1, bel2, ranges, flags);
  ct67_ellem<<<5376, 256, 0, stream>>>(adj00, b01, adj11, b12, adj22,
                                       bel0, bel1, bel2, ranges, ell, nnz,
                                       x0, pe0, Wf0, bf0, Wp0, x1, pe1, Wf1, bf1, Wp1,
                                       x2, pe2, Wf2, bf2, Wp2, hbuf, flags);
  for (int l = 0; l < 2; l++) {
    ct67_qkv<<<720, 512, 0, stream>>>(hbuf, Wq, bq, Wk, bk, Wv, bv, qb, kb, vb, l, flags);
    CellularTransformer_67345087201410_kernel<<<1920, 512, 0, stream>>>(
        qb, kb, vb, Wo, bo, adj00, b01, adj11, b12, adj22,
        bel0, bel1, bel2, ranges, ell, nnz, ellok, obuf, l, flags);
    ct67_ffn<<<768, 256, 0, stream>>>(hbuf, obuf, hbuf, Wff1, bff1, Wff2, bff2,
                                      g1, be1, g2, be2, l, flags);
  }
  ct67_poolp<<<dim3(8, 32), 64, 0, stream>>>(hbuf, ranges, ppart);
  ct67_poolmlp<<<1, 512, 0, stream>>>(ppart, ranges, Wh1, bh1, Wh2, bh2, Wh3, bh3,
                                      (float*)d_out, flags);
}